// Round 1
// baseline (3747.990 us; speedup 1.0000x reference)
//
#include <hip/hip_runtime.h>
#include <math.h>

#define P_   3
#define L_   6
#define CPL_ 32
#define C_   192
#define HID_ 64

__device__ __forceinline__ float bf2f(unsigned short u) {
    return __uint_as_float(((unsigned int)u) << 16);
}

// ---------------------------------------------------------------------------
// Transpose planes (N,P,C,256,256) f32  ->  (N,P,65536,C) bf16   (unchanged)
// ---------------------------------------------------------------------------
__global__ __launch_bounds__(256) void transpose_kernel(
    const float* __restrict__ in, unsigned short* __restrict__ out)
{
    __shared__ __align__(16) float tile[32][196];
    const int np   = blockIdx.x >> 11;
    const int pix0 = (blockIdx.x & 2047) << 5;
    const float* src = in + (size_t)np * C_ * 65536;
    uint2* dst = (uint2*)(out + (size_t)np * 65536 * C_);
    const int t = threadIdx.x;

    #pragma unroll
    for (int it = 0; it < 24; ++it) {
        int idx = it * 256 + t;
        int Cc  = idx >> 5;
        int px  = idx & 31;
        tile[px][Cc] = src[(size_t)Cc * 65536 + pix0 + px];
    }
    __syncthreads();
    #pragma unroll
    for (int it = 0; it < 6; ++it) {
        int idx = it * 256 + t;
        int cq  = idx % 48;
        int px  = idx / 48;
        float4 fv = *(const float4*)&tile[px][4 * cq];
        unsigned int u0 = __float_as_uint(fv.x), u1 = __float_as_uint(fv.y);
        unsigned int u2 = __float_as_uint(fv.z), u3 = __float_as_uint(fv.w);
        u0 = (u0 + 0x7fffu + ((u0 >> 16) & 1)) >> 16;
        u1 = (u1 + 0x7fffu + ((u1 >> 16) & 1)) >> 16;
        u2 = (u2 + 0x7fffu + ((u2 >> 16) & 1)) >> 16;
        u3 = (u3 + 0x7fffu + ((u3 >> 16) & 1)) >> 16;
        uint2 pk;
        pk.x = u0 | (u1 << 16);
        pk.y = u2 | (u3 << 16);
        dst[(size_t)(pix0 + px) * 48 + cq] = pk;
    }
}

// ---------------------------------------------------------------------------
// NEW: persistent waves, 8 points/wave, weights LDS-resident, 1-ahead gather
// prefetch. Steady-state VMEM = 36 gathers + 1 store per point only.
//
// LDS layout (floats):
//   w1s   [12288]  swizzled: word(cg,h) = cg*64 + (h ^ ((cg&31)<<1))
//   b1s   [384]
//   w2s   [1920]
//   b2s   [32]
//   cds   [192]    this block's 64 points' coords
//   per-wave (600 each): feat[192], dz[384], o[24]
// total = 19616 floats = 78464 B  -> 2 blocks/CU
// ---------------------------------------------------------------------------
struct Pref {
    unsigned short u[36];                 // 3 planes x 4 corners x 3 ch/lane
    float wx0[3], wx1[3], wy0[3], wy1[3];
    float vm[12];
};

__global__ __launch_bounds__(512, 3) void point2(
    const unsigned short* __restrict__ planes_bf,   // (NP,HW,C) bf16
    const float* __restrict__ coords,
    const float* __restrict__ w1,       // (L, CPL, HID)
    const float* __restrict__ b1,       // (L, HID)
    const float* __restrict__ w2,       // (L, HID, 5)
    const float* __restrict__ b2,       // (L, 5)
    const float* __restrict__ betap,
    float* __restrict__ out)            // (N*M, 17)
{
    extern __shared__ float sm[];
    float* w1s = sm;                 // 12288
    float* b1s = sm + 12288;         // 384
    float* w2s = sm + 12672;         // 1920
    float* b2s = sm + 14592;         // 32
    float* cds = sm + 14624;         // 192
    float* pwv = sm + 14816;         // 8 * 600

    const int tid  = threadIdx.x;
    const int wave = tid >> 6;
    const int lane = tid & 63;
    float* feat_s = pwv + wave * 600;
    float* dz_s   = feat_s + 192;
    float* o_s    = dz_s + 384;

    // ---- stage weights + coords into LDS (once per block) ----
    #pragma unroll
    for (int it = 0; it < 24; ++it) {
        int idx = it * 512 + tid;            // 0..12287
        int cg = idx >> 6, h = idx & 63;
        w1s[cg * 64 + (h ^ ((cg & 31) << 1))] = w1[idx];
    }
    if (tid < 384) b1s[tid] = b1[tid];
    #pragma unroll
    for (int it = 0; it < 4; ++it) {
        int idx = it * 512 + tid;
        if (idx < 1920) w2s[idx] = w2[idx];
    }
    if (tid < 30)  b2s[tid] = b2[tid];
    if (tid < 192) cds[tid] = coords[(size_t)blockIdx.x * 192 + tid];
    __syncthreads();

    const float beta = betap[0];
    const int gw = blockIdx.x * 8 + wave;          // global wave id, 8 pts each
    const int n  = gw >> 13;                        // (gw*8)>>16
    const unsigned short* pb = planes_bf + (size_t)n * 3 * 65536 * C_;

    // ---- issue: compute addresses for point i, fire 36 gather loads ----
    auto issue = [&](int i, Pref& P) {
        const int pt3 = (wave * 8 + i) * 3;
        const float cx = cds[pt3 + 0];
        const float cy = cds[pt3 + 1];
        const float cz = cds[pt3 + 2];
        const float pjx[3] = {cx, cx, cz};
        const float pjy[3] = {cy, cz, cy};
        #pragma unroll
        for (int p = 0; p < 3; ++p) {
            float px = (pjx[p] + 1.0f) * 128.0f - 0.5f;
            float py = (pjy[p] + 1.0f) * 128.0f - 0.5f;
            float x0f = floorf(px), y0f = floorf(py);
            P.wx1[p] = px - x0f; P.wx0[p] = 1.0f - P.wx1[p];
            P.wy1[p] = py - y0f; P.wy0[p] = 1.0f - P.wy1[p];
            int x0 = (int)x0f, y0 = (int)y0f;
            int x1 = x0 + 1,  y1 = y0 + 1;
            int xc0 = min(max(x0, 0), 255), xc1 = min(max(x1, 0), 255);
            int yc0 = min(max(y0, 0), 255), yc1 = min(max(y1, 0), 255);
            float vx0 = (x0 >= 0 && x0 < 256) ? 1.f : 0.f;
            float vx1 = (x1 >= 0 && x1 < 256) ? 1.f : 0.f;
            float vy0 = (y0 >= 0 && y0 < 256) ? 1.f : 0.f;
            float vy1 = (y1 >= 0 && y1 < 256) ? 1.f : 0.f;
            int pixi[4];
            pixi[0] = yc0 * 256 + xc0; P.vm[p * 4 + 0] = vx0 * vy0;
            pixi[1] = yc0 * 256 + xc1; P.vm[p * 4 + 1] = vx1 * vy0;
            pixi[2] = yc1 * 256 + xc0; P.vm[p * 4 + 2] = vx0 * vy1;
            pixi[3] = yc1 * 256 + xc1; P.vm[p * 4 + 3] = vx1 * vy1;
            const unsigned short* bp = pb + (size_t)p * 65536 * C_;
            #pragma unroll
            for (int j = 0; j < 4; ++j) {
                const unsigned short* a = bp + (size_t)pixi[j] * C_ + lane;
                P.u[(p * 4 + j) * 3 + 0] = a[0];
                P.u[(p * 4 + j) * 3 + 1] = a[64];
                P.u[(p * 4 + j) * 3 + 2] = a[128];
            }
        }
    };

    // ---- consume: bilinear -> feat (to LDS) + gradient combos (regs) ----
    auto consume = [&](const Pref& P, float (&gxc)[9], float (&gyc)[9]) {
        #pragma unroll
        for (int k = 0; k < 3; ++k) {
            float f = 0.f;
            #pragma unroll
            for (int p = 0; p < 3; ++p) {
                float g0 = bf2f(P.u[(p * 4 + 0) * 3 + k]) * P.vm[p * 4 + 0];
                float g1 = bf2f(P.u[(p * 4 + 1) * 3 + k]) * P.vm[p * 4 + 1];
                float g2 = bf2f(P.u[(p * 4 + 2) * 3 + k]) * P.vm[p * 4 + 2];
                float g3 = bf2f(P.u[(p * 4 + 3) * 3 + k]) * P.vm[p * 4 + 3];
                f += P.wx0[p] * P.wy0[p] * g0 + P.wx1[p] * P.wy0[p] * g1
                   + P.wx0[p] * P.wy1[p] * g2 + P.wx1[p] * P.wy1[p] * g3;
                gxc[p * 3 + k] = P.wy0[p] * (g1 - g0) + P.wy1[p] * (g3 - g2);
                gyc[p * 3 + k] = P.wx0[p] * (g2 - g0) + P.wx1[p] * (g3 - g1);
            }
            feat_s[lane + 64 * k] = f * (1.0f / 3.0f);
        }
        asm volatile("s_waitcnt lgkmcnt(0)" ::: "memory");
    };

    // ---- tail: MLP fwd + dfeat + grad dots + epilogue + store ----
    auto tail = [&](int i, const float (&gxc)[9], const float (&gyc)[9]) {
        #pragma unroll
        for (int l = 0; l < L_; ++l) {
            float b1l = b1s[l * HID_ + lane];
            const float* w2l = &w2s[(l * HID_ + lane) * 5];
            float w20 = w2l[0], w21 = w2l[1], w22 = w2l[2], w23 = w2l[3];

            float z0 = b1l, z1 = 0.f;
            #pragma unroll
            for (int q = 0; q < 8; ++q) {
                float4 fv = *(const float4*)&feat_s[l * CPL_ + 4 * q];
                z0 = fmaf(fv.x, w1s[((l*CPL_ + 4*q + 0) << 6) + (lane ^ (((4*q + 0) & 31) << 1))], z0);
                z1 = fmaf(fv.y, w1s[((l*CPL_ + 4*q + 1) << 6) + (lane ^ (((4*q + 1) & 31) << 1))], z1);
                z0 = fmaf(fv.z, w1s[((l*CPL_ + 4*q + 2) << 6) + (lane ^ (((4*q + 2) & 31) << 1))], z0);
                z1 = fmaf(fv.w, w1s[((l*CPL_ + 4*q + 3) << 6) + (lane ^ (((4*q + 3) & 31) << 1))], z1);
            }
            float z  = z0 + z1;
            float e  = expf(-fabsf(z));
            float sp = fmaxf(z, 0.f) + log1pf(e);
            float sg = ((z > 0.f) ? 1.0f : e) / (1.0f + e);   // sigmoid(z)
            dz_s[l * HID_ + lane] = sg * w20;

            float o0 = sp * w20, o1 = sp * w21, o2 = sp * w22, o3 = sp * w23;
            float u  = (lane & 1) ? o1 : o0;
            float uw = (lane & 1) ? o0 : o1;
            u += __shfl_xor(uw, 1, 64);
            float v  = (lane & 1) ? o3 : o2;
            float vw = (lane & 1) ? o2 : o3;
            v += __shfl_xor(vw, 1, 64);
            float tt = (lane & 2) ? v : u;
            float tw = (lane & 2) ? u : v;
            tt += __shfl_xor(tw, 2, 64);
            tt += __shfl_xor(tt, 4, 64);
            tt += __shfl_xor(tt, 8, 64);
            tt += __shfl_xor(tt, 16, 64);
            tt += __shfl_xor(tt, 32, 64);
            if ((lane >> 2) == l)
                o_s[lane] = tt + b2s[l * 5 + (lane & 3)];
        }
        asm volatile("s_waitcnt lgkmcnt(0)" ::: "memory");

        // ---- dfeat from LDS w1 (b64 reads, XOR-deswizzle, 4-way max) ----
        float df[3];
        const int Cx = (lane & 31) << 1;
        #pragma unroll
        for (int k = 0; k < 3; ++k) {
            const int cg = lane + 64 * k;
            const float* wr  = &w1s[cg << 6];
            const float* dzr = &dz_s[(cg >> 5) * HID_];
            float a0 = 0.f, a1 = 0.f;
            #pragma unroll
            for (int h2 = 0; h2 < 32; ++h2) {
                float2 wv = *(const float2*)&wr[(2 * h2) ^ Cx];
                float2 dv = *(const float2*)&dzr[2 * h2];
                a0 = fmaf(wv.x, dv.x, a0);
                a1 = fmaf(wv.y, dv.y, a1);
            }
            df[k] = a0 + a1;
        }

        // ---- gradient dots + wave reduction ----
        float ax[3] = {0.f, 0.f, 0.f};
        float ay[3] = {0.f, 0.f, 0.f};
        #pragma unroll
        for (int k = 0; k < 3; ++k)
            #pragma unroll
            for (int p = 0; p < 3; ++p) {
                ax[p] = fmaf(df[k], gxc[p * 3 + k], ax[p]);
                ay[p] = fmaf(df[k], gyc[p * 3 + k], ay[p]);
            }
        #pragma unroll
        for (int s = 1; s < 64; s <<= 1) {
            ax[0] += __shfl_xor(ax[0], s, 64);
            ax[1] += __shfl_xor(ax[1], s, 64);
            ax[2] += __shfl_xor(ax[2], s, 64);
            ay[0] += __shfl_xor(ay[0], s, 64);
            ay[1] += __shfl_xor(ay[1], s, 64);
            ay[2] += __shfl_xor(ay[2], s, 64);
        }
        const float F = 128.0f / 3.0f;
        float gcx = F * (ax[0] + ax[1]);
        float gcy = F * (ay[0] + ay[2]);
        float gcz = F * (ay[1] + ax[2]);

        // ---- epilogue ----
        const int pt3 = (wave * 8 + i) * 3;
        const float cx = cds[pt3 + 0];
        const float cy = cds[pt3 + 1];
        const float cz = cds[pt3 + 2];

        float olev[L_][4];
        #pragma unroll
        for (int l = 0; l < L_; ++l) {
            float4 ov = *(const float4*)&o_s[4 * l];
            olev[l][0] = ov.x; olev[l][1] = ov.y;
            olev[l][2] = ov.z; olev[l][3] = ov.w;
        }

        float r    = sqrtf(cx * cx + cy * cy + cz * cz);
        float smpl = r - 0.5f;
        float delta = 0.f;
        #pragma unroll
        for (int l = 0; l < L_; ++l) delta += olev[l][0];
        float sdf = smpl + delta;

        float ls[L_], sigma = 0.f;
        #pragma unroll
        for (int l = 0; l < L_; ++l) {
            float s = olev[l][0] + smpl;
            ls[l] = (1.0f / (1.0f + expf(s / beta))) / beta;
            sigma += ls[l];
        }
        float inv = 1.0f / (sigma + 1e-8f);
        float sem[L_];
        #pragma unroll
        for (int l = 0; l < L_; ++l) sem[l] = ls[l] * inv;

        float r0 = 0.f, r1 = 0.f, r2 = 0.f;
        #pragma unroll
        for (int l = 0; l < L_; ++l) {
            r0 = fmaf(olev[l][1], sem[l], r0);
            r1 = fmaf(olev[l][2], sem[l], r1);
            r2 = fmaf(olev[l][3], sem[l], r2);
        }
        float rgb0 = (1.0f / (1.0f + expf(-r0))) * 1.002f - 0.001f;
        float rgb1 = (1.0f / (1.0f + expf(-r1))) * 1.002f - 0.001f;
        float rgb2 = (1.0f / (1.0f + expf(-r2))) * 1.002f - 0.001f;

        float rinv = 1.0f / (r + 1e-8f);
        if (lane < 17) {
            float v =
                (lane == 0)  ? sdf :
                (lane == 1)  ? sigma :
                (lane == 2)  ? rgb0 :
                (lane == 3)  ? rgb1 :
                (lane == 4)  ? rgb2 :
                (lane == 5)  ? sem[0] :
                (lane == 6)  ? sem[1] :
                (lane == 7)  ? sem[2] :
                (lane == 8)  ? sem[3] :
                (lane == 9)  ? sem[4] :
                (lane == 10) ? sem[5] :
                (lane == 11) ? gcx + cx * rinv :
                (lane == 12) ? gcy + cy * rinv :
                (lane == 13) ? gcz + cz * rinv :
                (lane == 14) ? gcx :
                (lane == 15) ? gcy : gcz;
            out[(size_t)(gw * 8 + i) * 17 + lane] = v;
        }
    };

    // ---- software-pipelined point loop (A/B rotation, no runtime idx) ----
    Pref A, B;
    issue(0, A);
    #pragma unroll 1
    for (int i = 0; i < 8; i += 2) {
        {
            float gxc[9], gyc[9];
            consume(A, gxc, gyc);
            issue(i + 1, B);               // i <= 6, so i+1 always valid
            tail(i, gxc, gyc);
        }
        {
            float gxc[9], gyc[9];
            consume(B, gxc, gyc);
            if (i + 2 < 8) issue(i + 2, A);
            tail(i + 1, gxc, gyc);
        }
    }
}

// ---------------------------------------------------------------------------
// Fallback (no workspace): original 1-point/wave kernel, f32 plane reads.
// ---------------------------------------------------------------------------
__global__ __launch_bounds__(256, 4) void point_fallback(
    const float* __restrict__ planes_f32,          // (NP,C,HW) f32
    const float* __restrict__ coords,
    const float* __restrict__ w1,
    const float* __restrict__ b1,
    const float* __restrict__ w2,
    const float* __restrict__ b2,
    const float* __restrict__ betap,
    float* __restrict__ out)
{
    __shared__ __align__(16) float feat_s[4][C_];
    __shared__ __align__(16) float dz_s[4][L_ * HID_];
    __shared__ __align__(16) float o_s[4][24];

    const int wave  = threadIdx.x >> 6;
    const int lane  = threadIdx.x & 63;
    const int point = blockIdx.x * 4 + wave;
    const int n     = point >> 16;

    const float cx = coords[point * 3 + 0];
    const float cy = coords[point * 3 + 1];
    const float cz = coords[point * 3 + 2];

    const float pjx[3] = {cx, cx, cz};
    const float pjy[3] = {cy, cz, cy};

    float wx0[3], wx1[3], wy0[3], wy1[3];
    int   pixi[3][4];
    float vmk[3][4];
    #pragma unroll
    for (int p = 0; p < 3; ++p) {
        float px = (pjx[p] + 1.0f) * 128.0f - 0.5f;
        float py = (pjy[p] + 1.0f) * 128.0f - 0.5f;
        float x0f = floorf(px), y0f = floorf(py);
        wx1[p] = px - x0f; wx0[p] = 1.0f - wx1[p];
        wy1[p] = py - y0f; wy0[p] = 1.0f - wy1[p];
        int x0 = (int)x0f, y0 = (int)y0f;
        int x1 = x0 + 1,  y1 = y0 + 1;
        int xc0 = min(max(x0, 0), 255), xc1 = min(max(x1, 0), 255);
        int yc0 = min(max(y0, 0), 255), yc1 = min(max(y1, 0), 255);
        float vx0 = (x0 >= 0 && x0 < 256) ? 1.f : 0.f;
        float vx1 = (x1 >= 0 && x1 < 256) ? 1.f : 0.f;
        float vy0 = (y0 >= 0 && y0 < 256) ? 1.f : 0.f;
        float vy1 = (y1 >= 0 && y1 < 256) ? 1.f : 0.f;
        pixi[p][0] = yc0 * 256 + xc0; vmk[p][0] = vx0 * vy0;
        pixi[p][1] = yc0 * 256 + xc1; vmk[p][1] = vx1 * vy0;
        pixi[p][2] = yc1 * 256 + xc0; vmk[p][2] = vx0 * vy1;
        pixi[p][3] = yc1 * 256 + xc1; vmk[p][3] = vx1 * vy1;
    }

    float g[3][4][3];
    #pragma unroll
    for (int p = 0; p < 3; ++p)
        #pragma unroll
        for (int ij = 0; ij < 4; ++ij)
            #pragma unroll
            for (int k = 0; k < 3; ++k) {
                int Cc = lane + 64 * k;
                size_t a = ((size_t)((n * 3 + p) * C_ + Cc)) * 65536 + pixi[p][ij];
                g[p][ij][k] = planes_f32[a] * vmk[p][ij];
            }

    #pragma unroll
    for (int k = 0; k < 3; ++k) {
        float f = 0.f;
        #pragma unroll
        for (int p = 0; p < 3; ++p) {
            f += wx0[p] * wy0[p] * g[p][0][k] + wx1[p] * wy0[p] * g[p][1][k]
               + wx0[p] * wy1[p] * g[p][2][k] + wx1[p] * wy1[p] * g[p][3][k];
        }
        feat_s[wave][lane + 64 * k] = f * (1.0f / 3.0f);
    }
    asm volatile("s_waitcnt lgkmcnt(0)" ::: "memory");

    #pragma unroll
    for (int l = 0; l < L_; ++l) {
        float b1l = b1[l * HID_ + lane];
        const float* w2l = w2 + (l * HID_ + lane) * 5;
        float w20 = w2l[0], w21 = w2l[1], w22 = w2l[2], w23 = w2l[3];

        float z0 = b1l, z1 = 0.f;
        #pragma unroll
        for (int q = 0; q < 8; ++q) {
            float4 fv = *(const float4*)&feat_s[wave][l * CPL_ + 4 * q];
            z0 = fmaf(fv.x, w1[(l * CPL_ + 4 * q + 0) * HID_ + lane], z0);
            z1 = fmaf(fv.y, w1[(l * CPL_ + 4 * q + 1) * HID_ + lane], z1);
            z0 = fmaf(fv.z, w1[(l * CPL_ + 4 * q + 2) * HID_ + lane], z0);
            z1 = fmaf(fv.w, w1[(l * CPL_ + 4 * q + 3) * HID_ + lane], z1);
        }
        float z  = z0 + z1;
        float e  = expf(-fabsf(z));
        float sp = fmaxf(z, 0.f) + log1pf(e);
        float sg = ((z > 0.f) ? 1.0f : e) / (1.0f + e);
        dz_s[wave][l * HID_ + lane] = sg * w20;

        float o0 = sp * w20, o1 = sp * w21, o2 = sp * w22, o3 = sp * w23;
        float u  = (lane & 1) ? o1 : o0;
        float uw = (lane & 1) ? o0 : o1;
        u += __shfl_xor(uw, 1, 64);
        float v  = (lane & 1) ? o3 : o2;
        float vw = (lane & 1) ? o2 : o3;
        v += __shfl_xor(vw, 1, 64);
        float tt = (lane & 2) ? v : u;
        float tw = (lane & 2) ? u : v;
        tt += __shfl_xor(tw, 2, 64);
        tt += __shfl_xor(tt, 4, 64);
        tt += __shfl_xor(tt, 8, 64);
        tt += __shfl_xor(tt, 16, 64);
        tt += __shfl_xor(tt, 32, 64);
        if ((lane >> 2) == l)
            o_s[wave][lane] = tt + b2[l * 5 + (lane & 3)];
    }
    asm volatile("s_waitcnt lgkmcnt(0)" ::: "memory");

    float df[3];
    #pragma unroll
    for (int k = 0; k < 3; ++k) {
        int cg = lane + 64 * k;
        const float* w1r = w1 + cg * HID_;
        const float* dzr = &dz_s[wave][(cg >> 5) * HID_];
        float a0 = 0.f, a1 = 0.f;
        #pragma unroll
        for (int h4 = 0; h4 < 16; ++h4) {
            float4 wv = *(const float4*)(w1r + 4 * h4);
            float4 dv = *(const float4*)(dzr + 4 * h4);
            a0 = fmaf(wv.x, dv.x, a0);
            a1 = fmaf(wv.y, dv.y, a1);
            a0 = fmaf(wv.z, dv.z, a0);
            a1 = fmaf(wv.w, dv.w, a1);
        }
        df[k] = a0 + a1;
    }

    float ax[3] = {0.f, 0.f, 0.f};
    float ay[3] = {0.f, 0.f, 0.f};
    #pragma unroll
    for (int k = 0; k < 3; ++k)
        #pragma unroll
        for (int p = 0; p < 3; ++p) {
            ax[p] = fmaf(df[k], wy0[p] * (g[p][1][k] - g[p][0][k])
                               + wy1[p] * (g[p][3][k] - g[p][2][k]), ax[p]);
            ay[p] = fmaf(df[k], wx0[p] * (g[p][2][k] - g[p][0][k])
                               + wx1[p] * (g[p][3][k] - g[p][1][k]), ay[p]);
        }
    #pragma unroll
    for (int s = 1; s < 64; s <<= 1) {
        ax[0] += __shfl_xor(ax[0], s, 64);
        ax[1] += __shfl_xor(ax[1], s, 64);
        ax[2] += __shfl_xor(ax[2], s, 64);
        ay[0] += __shfl_xor(ay[0], s, 64);
        ay[1] += __shfl_xor(ay[1], s, 64);
        ay[2] += __shfl_xor(ay[2], s, 64);
    }
    const float F = 128.0f / 3.0f;
    float gcx = F * (ax[0] + ax[1]);
    float gcy = F * (ay[0] + ay[2]);
    float gcz = F * (ay[1] + ax[2]);

    const float beta = betap[0];
    float olev[L_][4];
    #pragma unroll
    for (int l = 0; l < L_; ++l) {
        float4 ov = *(const float4*)&o_s[wave][4 * l];
        olev[l][0] = ov.x; olev[l][1] = ov.y;
        olev[l][2] = ov.z; olev[l][3] = ov.w;
    }

    float r    = sqrtf(cx * cx + cy * cy + cz * cz);
    float smpl = r - 0.5f;
    float delta = 0.f;
    #pragma unroll
    for (int l = 0; l < L_; ++l) delta += olev[l][0];
    float sdf = smpl + delta;

    float ls[L_], sigma = 0.f;
    #pragma unroll
    for (int l = 0; l < L_; ++l) {
        float s = olev[l][0] + smpl;
        ls[l] = (1.0f / (1.0f + expf(s / beta))) / beta;
        sigma += ls[l];
    }
    float inv = 1.0f / (sigma + 1e-8f);
    float sem[L_];
    #pragma unroll
    for (int l = 0; l < L_; ++l) sem[l] = ls[l] * inv;

    float r0 = 0.f, r1 = 0.f, r2 = 0.f;
    #pragma unroll
    for (int l = 0; l < L_; ++l) {
        r0 = fmaf(olev[l][1], sem[l], r0);
        r1 = fmaf(olev[l][2], sem[l], r1);
        r2 = fmaf(olev[l][3], sem[l], r2);
    }
    float rgb0 = (1.0f / (1.0f + expf(-r0))) * 1.002f - 0.001f;
    float rgb1 = (1.0f / (1.0f + expf(-r1))) * 1.002f - 0.001f;
    float rgb2 = (1.0f / (1.0f + expf(-r2))) * 1.002f - 0.001f;

    float rinv = 1.0f / (r + 1e-8f);
    if (lane < 17) {
        float v =
            (lane == 0)  ? sdf :
            (lane == 1)  ? sigma :
            (lane == 2)  ? rgb0 :
            (lane == 3)  ? rgb1 :
            (lane == 4)  ? rgb2 :
            (lane == 5)  ? sem[0] :
            (lane == 6)  ? sem[1] :
            (lane == 7)  ? sem[2] :
            (lane == 8)  ? sem[3] :
            (lane == 9)  ? sem[4] :
            (lane == 10) ? sem[5] :
            (lane == 11) ? gcx + cx * rinv :
            (lane == 12) ? gcy + cy * rinv :
            (lane == 13) ? gcz + cz * rinv :
            (lane == 14) ? gcx :
            (lane == 15) ? gcy : gcz;
        out[(size_t)point * 17 + lane] = v;
    }
}

extern "C" void kernel_launch(void* const* d_in, const int* in_sizes, int n_in,
                              void* d_out, int out_size, void* d_ws, size_t ws_size,
                              hipStream_t stream)
{
    const float* planes = (const float*)d_in[0];
    const float* coords = (const float*)d_in[1];
    const float* w1     = (const float*)d_in[2];
    const float* b1     = (const float*)d_in[3];
    const float* w2     = (const float*)d_in[4];
    const float* b2     = (const float*)d_in[5];
    const float* beta   = (const float*)d_in[6];
    float* out = (float*)d_out;

    const size_t need = (size_t)6 * 65536 * C_ * sizeof(unsigned short); // 151 MB
    const int shmem = 19616 * 4;   // 78464 B dynamic LDS for point2

    if (ws_size >= need) {
        static bool attr_done = false;
        if (!attr_done) {
            (void)hipFuncSetAttribute(reinterpret_cast<const void*>(&point2),
                                      hipFuncAttributeMaxDynamicSharedMemorySize,
                                      shmem);
            attr_done = true;
        }
        unsigned short* tp = (unsigned short*)d_ws;
        transpose_kernel<<<6 * 2048, 256, 0, stream>>>(planes, tp);
        point2<<<2048, 512, shmem, stream>>>(
            tp, coords, w1, b1, w2, b2, beta, out);
    } else {
        point_fallback<<<131072 / 4, 256, 0, stream>>>(
            planes, coords, w1, b1, w2, b2, beta, out);
    }
}

// Round 2
// 1938.697 us; speedup vs baseline: 1.9333x; 1.9333x over previous
//
#include <hip/hip_runtime.h>
#include <math.h>

#define P_   3
#define L_   6
#define CPL_ 32
#define C_   192
#define HID_ 64

__device__ __forceinline__ float bf2f(unsigned short u) {
    return __uint_as_float(((unsigned int)u) << 16);
}

// ---------------------------------------------------------------------------
// Transpose planes (N,P,C,256,256) f32  ->  (N,P,65536,C) bf16   (unchanged)
// ---------------------------------------------------------------------------
__global__ __launch_bounds__(256) void transpose_kernel(
    const float* __restrict__ in, unsigned short* __restrict__ out)
{
    __shared__ __align__(16) float tile[32][196];
    const int np   = blockIdx.x >> 11;
    const int pix0 = (blockIdx.x & 2047) << 5;
    const float* src = in + (size_t)np * C_ * 65536;
    uint2* dst = (uint2*)(out + (size_t)np * 65536 * C_);
    const int t = threadIdx.x;

    #pragma unroll
    for (int it = 0; it < 24; ++it) {
        int idx = it * 256 + t;
        int Cc  = idx >> 5;
        int px  = idx & 31;
        tile[px][Cc] = src[(size_t)Cc * 65536 + pix0 + px];
    }
    __syncthreads();
    #pragma unroll
    for (int it = 0; it < 6; ++it) {
        int idx = it * 256 + t;
        int cq  = idx % 48;
        int px  = idx / 48;
        float4 fv = *(const float4*)&tile[px][4 * cq];
        unsigned int u0 = __float_as_uint(fv.x), u1 = __float_as_uint(fv.y);
        unsigned int u2 = __float_as_uint(fv.z), u3 = __float_as_uint(fv.w);
        u0 = (u0 + 0x7fffu + ((u0 >> 16) & 1)) >> 16;
        u1 = (u1 + 0x7fffu + ((u1 >> 16) & 1)) >> 16;
        u2 = (u2 + 0x7fffu + ((u2 >> 16) & 1)) >> 16;
        u3 = (u3 + 0x7fffu + ((u3 >> 16) & 1)) >> 16;
        uint2 pk;
        pk.x = u0 | (u1 << 16);
        pk.y = u2 | (u3 << 16);
        dst[(size_t)(pix0 + px) * 48 + cq] = pk;
    }
}

// ---------------------------------------------------------------------------
// Persistent waves, 8 points/wave, weights LDS-resident.
// v2: NO prefetch structs / lambdas — straight-line per-point loop, all state
// in constant-indexed locals (SROA-safe). TLP (4 waves/SIMD) hides gather
// latency; steady-state VMEM = 36 gathers + 1 store per point.
//
// LDS layout (floats):
//   w1s [12288]  swizzled: word(cg,h) = cg*64 + (h ^ ((cg&31)<<1))
//   b1s [384]  w2s [1920]  b2s [32]  cds [192]
//   per-wave (600): feat[192], dz[384], o[24]
// total 19616 floats = 78464 B -> 2 blocks/CU
// ---------------------------------------------------------------------------
__global__ __launch_bounds__(512, 4) void point2(
    const unsigned short* __restrict__ planes_bf,   // (NP,HW,C) bf16
    const float* __restrict__ coords,
    const float* __restrict__ w1,       // (L, CPL, HID)
    const float* __restrict__ b1,       // (L, HID)
    const float* __restrict__ w2,       // (L, HID, 5)
    const float* __restrict__ b2,       // (L, 5)
    const float* __restrict__ betap,
    float* __restrict__ out)            // (N*M, 17)
{
    extern __shared__ float sm[];
    float* w1s = sm;                 // 12288
    float* b1s = sm + 12288;         // 384
    float* w2s = sm + 12672;         // 1920
    float* b2s = sm + 14592;         // 32
    float* cds = sm + 14624;         // 192
    float* pwv = sm + 14816;         // 8 * 600

    const int tid  = threadIdx.x;
    const int wave = tid >> 6;
    const int lane = tid & 63;
    float* feat_s = pwv + wave * 600;
    float* dz_s   = feat_s + 192;
    float* o_s    = dz_s + 384;

    // ---- stage weights + coords into LDS (once per block) ----
    #pragma unroll
    for (int it = 0; it < 24; ++it) {
        int idx = it * 512 + tid;            // 0..12287
        int cg = idx >> 6, h = idx & 63;
        w1s[cg * 64 + (h ^ ((cg & 31) << 1))] = w1[idx];
    }
    if (tid < 384) b1s[tid] = b1[tid];
    #pragma unroll
    for (int it = 0; it < 4; ++it) {
        int idx = it * 512 + tid;
        if (idx < 1920) w2s[idx] = w2[idx];
    }
    if (tid < 30)  b2s[tid] = b2[tid];
    if (tid < 192) cds[tid] = coords[(size_t)blockIdx.x * 192 + tid];
    __syncthreads();

    // ---- per-lane weight registers (reused by all 8 points) ----
    float b1r[L_], b2r[L_];
    #pragma unroll
    for (int l = 0; l < L_; ++l) {
        b1r[l] = b1s[l * HID_ + lane];
        b2r[l] = b2s[l * 5 + (lane & 3)];
    }

    const float beta = betap[0];
    const int gw = blockIdx.x * 8 + wave;          // global wave id, 8 pts each
    const int n  = blockIdx.x >> 10;               // batch index (uniform/block)
    const unsigned short* pb = planes_bf + (size_t)n * 3 * 65536 * C_;
    const int Cx = (lane & 31) << 1;               // dfeat de-swizzle

    #pragma unroll 1
    for (int i = 0; i < 8; ++i) {
        const int pt3 = (wave * 8 + i) * 3;
        const float cx = cds[pt3 + 0];
        const float cy = cds[pt3 + 1];
        const float cz = cds[pt3 + 2];
        const float pjx[3] = {cx, cx, cz};
        const float pjy[3] = {cy, cz, cy};

        // ---- bilinear setup ----
        float wx0[3], wx1[3], wy0[3], wy1[3], vm[3][4];
        int   pixi[3][4];
        #pragma unroll
        for (int p = 0; p < 3; ++p) {
            float px = (pjx[p] + 1.0f) * 128.0f - 0.5f;
            float py = (pjy[p] + 1.0f) * 128.0f - 0.5f;
            float x0f = floorf(px), y0f = floorf(py);
            wx1[p] = px - x0f; wx0[p] = 1.0f - wx1[p];
            wy1[p] = py - y0f; wy0[p] = 1.0f - wy1[p];
            int x0 = (int)x0f, y0 = (int)y0f;
            int x1 = x0 + 1,  y1 = y0 + 1;
            int xc0 = min(max(x0, 0), 255), xc1 = min(max(x1, 0), 255);
            int yc0 = min(max(y0, 0), 255), yc1 = min(max(y1, 0), 255);
            float vx0 = (x0 >= 0 && x0 < 256) ? 1.f : 0.f;
            float vx1 = (x1 >= 0 && x1 < 256) ? 1.f : 0.f;
            float vy0 = (y0 >= 0 && y0 < 256) ? 1.f : 0.f;
            float vy1 = (y1 >= 0 && y1 < 256) ? 1.f : 0.f;
            pixi[p][0] = yc0 * 256 + xc0; vm[p][0] = vx0 * vy0;
            pixi[p][1] = yc0 * 256 + xc1; vm[p][1] = vx1 * vy0;
            pixi[p][2] = yc1 * 256 + xc0; vm[p][2] = vx0 * vy1;
            pixi[p][3] = yc1 * 256 + xc1; vm[p][3] = vx1 * vy1;
        }

        // ---- gather 36 bf16 values (independent loads; compiler batches) ----
        unsigned short us[3][4][3];
        #pragma unroll
        for (int p = 0; p < 3; ++p) {
            const unsigned short* bp = pb + (size_t)p * 65536 * C_;
            #pragma unroll
            for (int j = 0; j < 4; ++j) {
                const unsigned short* a = bp + (size_t)pixi[p][j] * C_ + lane;
                us[p][j][0] = a[0];
                us[p][j][1] = a[64];
                us[p][j][2] = a[128];
            }
        }

        // ---- bilinear combine -> feat (LDS) + gradient combos (regs) ----
        float gxc[9], gyc[9];
        #pragma unroll
        for (int k = 0; k < 3; ++k) {
            float f = 0.f;
            #pragma unroll
            for (int p = 0; p < 3; ++p) {
                float g0 = bf2f(us[p][0][k]) * vm[p][0];
                float g1 = bf2f(us[p][1][k]) * vm[p][1];
                float g2 = bf2f(us[p][2][k]) * vm[p][2];
                float g3 = bf2f(us[p][3][k]) * vm[p][3];
                f += wx0[p] * wy0[p] * g0 + wx1[p] * wy0[p] * g1
                   + wx0[p] * wy1[p] * g2 + wx1[p] * wy1[p] * g3;
                gxc[p * 3 + k] = wy0[p] * (g1 - g0) + wy1[p] * (g3 - g2);
                gyc[p * 3 + k] = wx0[p] * (g2 - g0) + wx1[p] * (g3 - g1);
            }
            feat_s[lane + 64 * k] = f * (1.0f / 3.0f);
        }
        asm volatile("s_waitcnt lgkmcnt(0)" ::: "memory");

        // ---- MLP forward: lane == hidden unit ----
        #pragma unroll
        for (int l = 0; l < L_; ++l) {
            const float* w2l = &w2s[(l * HID_ + lane) * 5];
            float w20 = w2l[0], w21 = w2l[1], w22 = w2l[2], w23 = w2l[3];

            float z0 = b1r[l], z1 = 0.f;
            #pragma unroll
            for (int q = 0; q < 8; ++q) {
                float4 fv = *(const float4*)&feat_s[l * CPL_ + 4 * q];
                z0 = fmaf(fv.x, w1s[((l*CPL_ + 4*q + 0) << 6) + (lane ^ (((4*q + 0) & 31) << 1))], z0);
                z1 = fmaf(fv.y, w1s[((l*CPL_ + 4*q + 1) << 6) + (lane ^ (((4*q + 1) & 31) << 1))], z1);
                z0 = fmaf(fv.z, w1s[((l*CPL_ + 4*q + 2) << 6) + (lane ^ (((4*q + 2) & 31) << 1))], z0);
                z1 = fmaf(fv.w, w1s[((l*CPL_ + 4*q + 3) << 6) + (lane ^ (((4*q + 3) & 31) << 1))], z1);
            }
            float z  = z0 + z1;
            float e  = expf(-fabsf(z));
            float sp = fmaxf(z, 0.f) + log1pf(e);
            float sg = ((z > 0.f) ? 1.0f : e) / (1.0f + e);   // sigmoid(z)
            dz_s[l * HID_ + lane] = sg * w20;

            float o0 = sp * w20, o1 = sp * w21, o2 = sp * w22, o3 = sp * w23;
            float u  = (lane & 1) ? o1 : o0;
            float uw = (lane & 1) ? o0 : o1;
            u += __shfl_xor(uw, 1, 64);
            float v  = (lane & 1) ? o3 : o2;
            float vw = (lane & 1) ? o2 : o3;
            v += __shfl_xor(vw, 1, 64);
            float tt = (lane & 2) ? v : u;
            float tw = (lane & 2) ? u : v;
            tt += __shfl_xor(tw, 2, 64);
            tt += __shfl_xor(tt, 4, 64);
            tt += __shfl_xor(tt, 8, 64);
            tt += __shfl_xor(tt, 16, 64);
            tt += __shfl_xor(tt, 32, 64);
            if ((lane >> 2) == l)
                o_s[lane] = tt + b2r[l];
        }
        asm volatile("s_waitcnt lgkmcnt(0)" ::: "memory");

        // ---- dfeat from LDS w1 (b64 reads, XOR-deswizzle, b64 floor) ----
        float df[3];
        #pragma unroll
        for (int k = 0; k < 3; ++k) {
            const int cg = lane + 64 * k;
            const float* wr  = &w1s[cg << 6];
            const float* dzr = &dz_s[(cg >> 5) * HID_];
            float a0 = 0.f, a1 = 0.f;
            #pragma unroll
            for (int h2 = 0; h2 < 32; ++h2) {
                float2 wv = *(const float2*)&wr[(2 * h2) ^ Cx];
                float2 dv = *(const float2*)&dzr[2 * h2];
                a0 = fmaf(wv.x, dv.x, a0);
                a1 = fmaf(wv.y, dv.y, a1);
            }
            df[k] = a0 + a1;
        }

        // ---- gradient dots + wave reduction ----
        float ax[3] = {0.f, 0.f, 0.f};
        float ay[3] = {0.f, 0.f, 0.f};
        #pragma unroll
        for (int k = 0; k < 3; ++k)
            #pragma unroll
            for (int p = 0; p < 3; ++p) {
                ax[p] = fmaf(df[k], gxc[p * 3 + k], ax[p]);
                ay[p] = fmaf(df[k], gyc[p * 3 + k], ay[p]);
            }
        #pragma unroll
        for (int s = 1; s < 64; s <<= 1) {
            ax[0] += __shfl_xor(ax[0], s, 64);
            ax[1] += __shfl_xor(ax[1], s, 64);
            ax[2] += __shfl_xor(ax[2], s, 64);
            ay[0] += __shfl_xor(ay[0], s, 64);
            ay[1] += __shfl_xor(ay[1], s, 64);
            ay[2] += __shfl_xor(ay[2], s, 64);
        }
        const float F = 128.0f / 3.0f;
        float gcx = F * (ax[0] + ax[1]);
        float gcy = F * (ay[0] + ay[2]);
        float gcz = F * (ay[1] + ax[2]);

        // ---- epilogue ----
        float olev[L_][4];
        #pragma unroll
        for (int l = 0; l < L_; ++l) {
            float4 ov = *(const float4*)&o_s[4 * l];
            olev[l][0] = ov.x; olev[l][1] = ov.y;
            olev[l][2] = ov.z; olev[l][3] = ov.w;
        }

        float r    = sqrtf(cx * cx + cy * cy + cz * cz);
        float smpl = r - 0.5f;
        float delta = 0.f;
        #pragma unroll
        for (int l = 0; l < L_; ++l) delta += olev[l][0];
        float sdf = smpl + delta;

        float ls[L_], sigma = 0.f;
        #pragma unroll
        for (int l = 0; l < L_; ++l) {
            float s = olev[l][0] + smpl;
            ls[l] = (1.0f / (1.0f + expf(s / beta))) / beta;
            sigma += ls[l];
        }
        float inv = 1.0f / (sigma + 1e-8f);
        float sem[L_];
        #pragma unroll
        for (int l = 0; l < L_; ++l) sem[l] = ls[l] * inv;

        float r0 = 0.f, r1 = 0.f, r2 = 0.f;
        #pragma unroll
        for (int l = 0; l < L_; ++l) {
            r0 = fmaf(olev[l][1], sem[l], r0);
            r1 = fmaf(olev[l][2], sem[l], r1);
            r2 = fmaf(olev[l][3], sem[l], r2);
        }
        float rgb0 = (1.0f / (1.0f + expf(-r0))) * 1.002f - 0.001f;
        float rgb1 = (1.0f / (1.0f + expf(-r1))) * 1.002f - 0.001f;
        float rgb2 = (1.0f / (1.0f + expf(-r2))) * 1.002f - 0.001f;

        float rinv = 1.0f / (r + 1e-8f);
        if (lane < 17) {
            float v =
                (lane == 0)  ? sdf :
                (lane == 1)  ? sigma :
                (lane == 2)  ? rgb0 :
                (lane == 3)  ? rgb1 :
                (lane == 4)  ? rgb2 :
                (lane == 5)  ? sem[0] :
                (lane == 6)  ? sem[1] :
                (lane == 7)  ? sem[2] :
                (lane == 8)  ? sem[3] :
                (lane == 9)  ? sem[4] :
                (lane == 10) ? sem[5] :
                (lane == 11) ? gcx + cx * rinv :
                (lane == 12) ? gcy + cy * rinv :
                (lane == 13) ? gcz + cz * rinv :
                (lane == 14) ? gcx :
                (lane == 15) ? gcy : gcz;
            out[(size_t)(gw * 8 + i) * 17 + lane] = v;
        }
    }
}

// ---------------------------------------------------------------------------
// Fallback (no workspace): original 1-point/wave kernel, f32 plane reads.
// ---------------------------------------------------------------------------
__global__ __launch_bounds__(256, 4) void point_fallback(
    const float* __restrict__ planes_f32,          // (NP,C,HW) f32
    const float* __restrict__ coords,
    const float* __restrict__ w1,
    const float* __restrict__ b1,
    const float* __restrict__ w2,
    const float* __restrict__ b2,
    const float* __restrict__ betap,
    float* __restrict__ out)
{
    __shared__ __align__(16) float feat_s[4][C_];
    __shared__ __align__(16) float dz_s[4][L_ * HID_];
    __shared__ __align__(16) float o_s[4][24];

    const int wave  = threadIdx.x >> 6;
    const int lane  = threadIdx.x & 63;
    const int point = blockIdx.x * 4 + wave;
    const int n     = point >> 16;

    const float cx = coords[point * 3 + 0];
    const float cy = coords[point * 3 + 1];
    const float cz = coords[point * 3 + 2];

    const float pjx[3] = {cx, cx, cz};
    const float pjy[3] = {cy, cz, cy};

    float wx0[3], wx1[3], wy0[3], wy1[3];
    int   pixi[3][4];
    float vmk[3][4];
    #pragma unroll
    for (int p = 0; p < 3; ++p) {
        float px = (pjx[p] + 1.0f) * 128.0f - 0.5f;
        float py = (pjy[p] + 1.0f) * 128.0f - 0.5f;
        float x0f = floorf(px), y0f = floorf(py);
        wx1[p] = px - x0f; wx0[p] = 1.0f - wx1[p];
        wy1[p] = py - y0f; wy0[p] = 1.0f - wy1[p];
        int x0 = (int)x0f, y0 = (int)y0f;
        int x1 = x0 + 1,  y1 = y0 + 1;
        int xc0 = min(max(x0, 0), 255), xc1 = min(max(x1, 0), 255);
        int yc0 = min(max(y0, 0), 255), yc1 = min(max(y1, 0), 255);
        float vx0 = (x0 >= 0 && x0 < 256) ? 1.f : 0.f;
        float vx1 = (x1 >= 0 && x1 < 256) ? 1.f : 0.f;
        float vy0 = (y0 >= 0 && y0 < 256) ? 1.f : 0.f;
        float vy1 = (y1 >= 0 && y1 < 256) ? 1.f : 0.f;
        pixi[p][0] = yc0 * 256 + xc0; vmk[p][0] = vx0 * vy0;
        pixi[p][1] = yc0 * 256 + xc1; vmk[p][1] = vx1 * vy0;
        pixi[p][2] = yc1 * 256 + xc0; vmk[p][2] = vx0 * vy1;
        pixi[p][3] = yc1 * 256 + xc1; vmk[p][3] = vx1 * vy1;
    }

    float g[3][4][3];
    #pragma unroll
    for (int p = 0; p < 3; ++p)
        #pragma unroll
        for (int ij = 0; ij < 4; ++ij)
            #pragma unroll
            for (int k = 0; k < 3; ++k) {
                int Cc = lane + 64 * k;
                size_t a = ((size_t)((n * 3 + p) * C_ + Cc)) * 65536 + pixi[p][ij];
                g[p][ij][k] = planes_f32[a] * vmk[p][ij];
            }

    #pragma unroll
    for (int k = 0; k < 3; ++k) {
        float f = 0.f;
        #pragma unroll
        for (int p = 0; p < 3; ++p) {
            f += wx0[p] * wy0[p] * g[p][0][k] + wx1[p] * wy0[p] * g[p][1][k]
               + wx0[p] * wy1[p] * g[p][2][k] + wx1[p] * wy1[p] * g[p][3][k];
        }
        feat_s[wave][lane + 64 * k] = f * (1.0f / 3.0f);
    }
    asm volatile("s_waitcnt lgkmcnt(0)" ::: "memory");

    #pragma unroll
    for (int l = 0; l < L_; ++l) {
        float b1l = b1[l * HID_ + lane];
        const float* w2l = w2 + (l * HID_ + lane) * 5;
        float w20 = w2l[0], w21 = w2l[1], w22 = w2l[2], w23 = w2l[3];

        float z0 = b1l, z1 = 0.f;
        #pragma unroll
        for (int q = 0; q < 8; ++q) {
            float4 fv = *(const float4*)&feat_s[wave][l * CPL_ + 4 * q];
            z0 = fmaf(fv.x, w1[(l * CPL_ + 4 * q + 0) * HID_ + lane], z0);
            z1 = fmaf(fv.y, w1[(l * CPL_ + 4 * q + 1) * HID_ + lane], z1);
            z0 = fmaf(fv.z, w1[(l * CPL_ + 4 * q + 2) * HID_ + lane], z0);
            z1 = fmaf(fv.w, w1[(l * CPL_ + 4 * q + 3) * HID_ + lane], z1);
        }
        float z  = z0 + z1;
        float e  = expf(-fabsf(z));
        float sp = fmaxf(z, 0.f) + log1pf(e);
        float sg = ((z > 0.f) ? 1.0f : e) / (1.0f + e);
        dz_s[wave][l * HID_ + lane] = sg * w20;

        float o0 = sp * w20, o1 = sp * w21, o2 = sp * w22, o3 = sp * w23;
        float u  = (lane & 1) ? o1 : o0;
        float uw = (lane & 1) ? o0 : o1;
        u += __shfl_xor(uw, 1, 64);
        float v  = (lane & 1) ? o3 : o2;
        float vw = (lane & 1) ? o2 : o3;
        v += __shfl_xor(vw, 1, 64);
        float tt = (lane & 2) ? v : u;
        float tw = (lane & 2) ? u : v;
        tt += __shfl_xor(tw, 2, 64);
        tt += __shfl_xor(tt, 4, 64);
        tt += __shfl_xor(tt, 8, 64);
        tt += __shfl_xor(tt, 16, 64);
        tt += __shfl_xor(tt, 32, 64);
        if ((lane >> 2) == l)
            o_s[wave][lane] = tt + b2[l * 5 + (lane & 3)];
    }
    asm volatile("s_waitcnt lgkmcnt(0)" ::: "memory");

    float df[3];
    #pragma unroll
    for (int k = 0; k < 3; ++k) {
        int cg = lane + 64 * k;
        const float* w1r = w1 + cg * HID_;
        const float* dzr = &dz_s[wave][(cg >> 5) * HID_];
        float a0 = 0.f, a1 = 0.f;
        #pragma unroll
        for (int h4 = 0; h4 < 16; ++h4) {
            float4 wv = *(const float4*)(w1r + 4 * h4);
            float4 dv = *(const float4*)(dzr + 4 * h4);
            a0 = fmaf(wv.x, dv.x, a0);
            a1 = fmaf(wv.y, dv.y, a1);
            a0 = fmaf(wv.z, dv.z, a0);
            a1 = fmaf(wv.w, dv.w, a1);
        }
        df[k] = a0 + a1;
    }

    float ax[3] = {0.f, 0.f, 0.f};
    float ay[3] = {0.f, 0.f, 0.f};
    #pragma unroll
    for (int k = 0; k < 3; ++k)
        #pragma unroll
        for (int p = 0; p < 3; ++p) {
            ax[p] = fmaf(df[k], wy0[p] * (g[p][1][k] - g[p][0][k])
                               + wy1[p] * (g[p][3][k] - g[p][2][k]), ax[p]);
            ay[p] = fmaf(df[k], wx0[p] * (g[p][2][k] - g[p][0][k])
                               + wx1[p] * (g[p][3][k] - g[p][1][k]), ay[p]);
        }
    #pragma unroll
    for (int s = 1; s < 64; s <<= 1) {
        ax[0] += __shfl_xor(ax[0], s, 64);
        ax[1] += __shfl_xor(ax[1], s, 64);
        ax[2] += __shfl_xor(ax[2], s, 64);
        ay[0] += __shfl_xor(ay[0], s, 64);
        ay[1] += __shfl_xor(ay[1], s, 64);
        ay[2] += __shfl_xor(ay[2], s, 64);
    }
    const float F = 128.0f / 3.0f;
    float gcx = F * (ax[0] + ax[1]);
    float gcy = F * (ay[0] + ay[2]);
    float gcz = F * (ay[1] + ax[2]);

    const float beta = betap[0];
    float olev[L_][4];
    #pragma unroll
    for (int l = 0; l < L_; ++l) {
        float4 ov = *(const float4*)&o_s[wave][4 * l];
        olev[l][0] = ov.x; olev[l][1] = ov.y;
        olev[l][2] = ov.z; olev[l][3] = ov.w;
    }

    float r    = sqrtf(cx * cx + cy * cy + cz * cz);
    float smpl = r - 0.5f;
    float delta = 0.f;
    #pragma unroll
    for (int l = 0; l < L_; ++l) delta += olev[l][0];
    float sdf = smpl + delta;

    float ls[L_], sigma = 0.f;
    #pragma unroll
    for (int l = 0; l < L_; ++l) {
        float s = olev[l][0] + smpl;
        ls[l] = (1.0f / (1.0f + expf(s / beta))) / beta;
        sigma += ls[l];
    }
    float inv = 1.0f / (sigma + 1e-8f);
    float sem[L_];
    #pragma unroll
    for (int l = 0; l < L_; ++l) sem[l] = ls[l] * inv;

    float r0 = 0.f, r1 = 0.f, r2 = 0.f;
    #pragma unroll
    for (int l = 0; l < L_; ++l) {
        r0 = fmaf(olev[l][1], sem[l], r0);
        r1 = fmaf(olev[l][2], sem[l], r1);
        r2 = fmaf(olev[l][3], sem[l], r2);
    }
    float rgb0 = (1.0f / (1.0f + expf(-r0))) * 1.002f - 0.001f;
    float rgb1 = (1.0f / (1.0f + expf(-r1))) * 1.002f - 0.001f;
    float rgb2 = (1.0f / (1.0f + expf(-r2))) * 1.002f - 0.001f;

    float rinv = 1.0f / (r + 1e-8f);
    if (lane < 17) {
        float v =
            (lane == 0)  ? sdf :
            (lane == 1)  ? sigma :
            (lane == 2)  ? rgb0 :
            (lane == 3)  ? rgb1 :
            (lane == 4)  ? rgb2 :
            (lane == 5)  ? sem[0] :
            (lane == 6)  ? sem[1] :
            (lane == 7)  ? sem[2] :
            (lane == 8)  ? sem[3] :
            (lane == 9)  ? sem[4] :
            (lane == 10) ? sem[5] :
            (lane == 11) ? gcx + cx * rinv :
            (lane == 12) ? gcy + cy * rinv :
            (lane == 13) ? gcz + cz * rinv :
            (lane == 14) ? gcx :
            (lane == 15) ? gcy : gcz;
        out[(size_t)point * 17 + lane] = v;
    }
}

extern "C" void kernel_launch(void* const* d_in, const int* in_sizes, int n_in,
                              void* d_out, int out_size, void* d_ws, size_t ws_size,
                              hipStream_t stream)
{
    const float* planes = (const float*)d_in[0];
    const float* coords = (const float*)d_in[1];
    const float* w1     = (const float*)d_in[2];
    const float* b1     = (const float*)d_in[3];
    const float* w2     = (const float*)d_in[4];
    const float* b2     = (const float*)d_in[5];
    const float* beta   = (const float*)d_in[6];
    float* out = (float*)d_out;

    const size_t need = (size_t)6 * 65536 * C_ * sizeof(unsigned short); // 151 MB
    const int shmem = 19616 * 4;   // 78464 B dynamic LDS for point2

    if (ws_size >= need) {
        static bool attr_done = false;
        if (!attr_done) {
            (void)hipFuncSetAttribute(reinterpret_cast<const void*>(&point2),
                                      hipFuncAttributeMaxDynamicSharedMemorySize,
                                      shmem);
            attr_done = true;
        }
        unsigned short* tp = (unsigned short*)d_ws;
        transpose_kernel<<<6 * 2048, 256, 0, stream>>>(planes, tp);
        point2<<<2048, 512, shmem, stream>>>(
            tp, coords, w1, b1, w2, b2, beta, out);
    } else {
        point_fallback<<<131072 / 4, 256, 0, stream>>>(
            planes, coords, w1, b1, w2, b2, beta, out);
    }
}

// Round 3
// 1159.923 us; speedup vs baseline: 3.2312x; 1.6714x over previous
//
#include <hip/hip_runtime.h>
#include <math.h>

#define P_   3
#define L_   6
#define CPL_ 32
#define C_   192
#define HID_ 64

__device__ __forceinline__ float bf2f(unsigned short u) {
    return __uint_as_float(((unsigned int)u) << 16);
}

// ---------------------------------------------------------------------------
// Transpose planes (N,P,C,256,256) f32  ->  (N,P,65536,C) bf16
// v3: float4 global reads (4x fewer VMEM instructions)
// ---------------------------------------------------------------------------
__global__ __launch_bounds__(256) void transpose_kernel(
    const float* __restrict__ in, unsigned short* __restrict__ out)
{
    __shared__ __align__(16) float tile[32][196];
    const int np   = blockIdx.x >> 11;
    const int pix0 = (blockIdx.x & 2047) << 5;
    const float* src = in + (size_t)np * C_ * 65536;
    uint2* dst = (uint2*)(out + (size_t)np * 65536 * C_);
    const int t = threadIdx.x;

    #pragma unroll
    for (int it = 0; it < 6; ++it) {
        int idx = it * 256 + t;               // 0..1535
        int Cc  = idx >> 3;                   // 0..191
        int pq  = idx & 7;                    // 0..7 -> px = 4*pq..4*pq+3
        float4 fv = *(const float4*)&src[(size_t)Cc * 65536 + pix0 + 4 * pq];
        tile[4 * pq + 0][Cc] = fv.x;
        tile[4 * pq + 1][Cc] = fv.y;
        tile[4 * pq + 2][Cc] = fv.z;
        tile[4 * pq + 3][Cc] = fv.w;
    }
    __syncthreads();
    #pragma unroll
    for (int it = 0; it < 6; ++it) {
        int idx = it * 256 + t;
        int cq  = idx % 48;
        int px  = idx / 48;
        float4 fv = *(const float4*)&tile[px][4 * cq];
        unsigned int u0 = __float_as_uint(fv.x), u1 = __float_as_uint(fv.y);
        unsigned int u2 = __float_as_uint(fv.z), u3 = __float_as_uint(fv.w);
        u0 = (u0 + 0x7fffu + ((u0 >> 16) & 1)) >> 16;
        u1 = (u1 + 0x7fffu + ((u1 >> 16) & 1)) >> 16;
        u2 = (u2 + 0x7fffu + ((u2 >> 16) & 1)) >> 16;
        u3 = (u3 + 0x7fffu + ((u3 >> 16) & 1)) >> 16;
        uint2 pk;
        pk.x = u0 | (u1 << 16);
        pk.y = u2 | (u3 << 16);
        dst[(size_t)(pix0 + px) * 48 + cq] = pk;
    }
}

// ---------------------------------------------------------------------------
// Persistent waves, 8 points/wave, weights LDS-resident.
// v3: amdgpu_waves_per_eu(2,4) — LDS caps occupancy at 4 waves/EU anyway, so
// let the register allocator use up to 128 VGPRs instead of spilling to fit
// a useless 8-waves/EU target (R2: VGPR=64, WRITE_SIZE=635MB of spill).
//
// LDS layout (floats):
//   w1s [12288]  swizzled: word(cg,h) = cg*64 + (h ^ ((cg&31)<<1))
//   b1s [384]  w2s [1920]  b2s [32]  cds [192]
//   per-wave (600): feat[192], dz[384], o[24]
// total 19616 floats = 78464 B -> 2 blocks/CU
// ---------------------------------------------------------------------------
__global__ __launch_bounds__(512)
__attribute__((amdgpu_waves_per_eu(2, 4))) void point2(
    const unsigned short* __restrict__ planes_bf,   // (NP,HW,C) bf16
    const float* __restrict__ coords,
    const float* __restrict__ w1,       // (L, CPL, HID)
    const float* __restrict__ b1,       // (L, HID)
    const float* __restrict__ w2,       // (L, HID, 5)
    const float* __restrict__ b2,       // (L, 5)
    const float* __restrict__ betap,
    float* __restrict__ out)            // (N*M, 17)
{
    extern __shared__ float sm[];
    float* w1s = sm;                 // 12288
    float* b1s = sm + 12288;         // 384
    float* w2s = sm + 12672;         // 1920
    float* b2s = sm + 14592;         // 32
    float* cds = sm + 14624;         // 192
    float* pwv = sm + 14816;         // 8 * 600

    const int tid  = threadIdx.x;
    const int wave = tid >> 6;
    const int lane = tid & 63;
    float* feat_s = pwv + wave * 600;
    float* dz_s   = feat_s + 192;
    float* o_s    = dz_s + 384;

    // ---- stage weights + coords into LDS (once per block) ----
    #pragma unroll
    for (int it = 0; it < 24; ++it) {
        int idx = it * 512 + tid;            // 0..12287
        int cg = idx >> 6, h = idx & 63;
        w1s[cg * 64 + (h ^ ((cg & 31) << 1))] = w1[idx];
    }
    if (tid < 384) b1s[tid] = b1[tid];
    #pragma unroll
    for (int it = 0; it < 4; ++it) {
        int idx = it * 512 + tid;
        if (idx < 1920) w2s[idx] = w2[idx];
    }
    if (tid < 30)  b2s[tid] = b2[tid];
    if (tid < 192) cds[tid] = coords[(size_t)blockIdx.x * 192 + tid];
    __syncthreads();

    // ---- per-lane weight registers (reused by all 8 points) ----
    float b1r[L_], b2r[L_];
    #pragma unroll
    for (int l = 0; l < L_; ++l) {
        b1r[l] = b1s[l * HID_ + lane];
        b2r[l] = b2s[l * 5 + (lane & 3)];
    }

    const float beta = betap[0];
    const int gw = blockIdx.x * 8 + wave;          // global wave id, 8 pts each
    const int n  = blockIdx.x >> 10;               // batch index (uniform/block)
    const unsigned short* pb = planes_bf + (size_t)n * 3 * 65536 * C_;
    const int Cx = (lane & 31) << 1;               // dfeat de-swizzle

    #pragma unroll 1
    for (int i = 0; i < 8; ++i) {
        const int pt3 = (wave * 8 + i) * 3;
        const float cx = cds[pt3 + 0];
        const float cy = cds[pt3 + 1];
        const float cz = cds[pt3 + 2];
        const float pjx[3] = {cx, cx, cz};
        const float pjy[3] = {cy, cz, cy};

        // ---- bilinear setup ----
        float wx0[3], wx1[3], wy0[3], wy1[3], vm[3][4];
        int   pixi[3][4];
        #pragma unroll
        for (int p = 0; p < 3; ++p) {
            float px = (pjx[p] + 1.0f) * 128.0f - 0.5f;
            float py = (pjy[p] + 1.0f) * 128.0f - 0.5f;
            float x0f = floorf(px), y0f = floorf(py);
            wx1[p] = px - x0f; wx0[p] = 1.0f - wx1[p];
            wy1[p] = py - y0f; wy0[p] = 1.0f - wy1[p];
            int x0 = (int)x0f, y0 = (int)y0f;
            int x1 = x0 + 1,  y1 = y0 + 1;
            int xc0 = min(max(x0, 0), 255), xc1 = min(max(x1, 0), 255);
            int yc0 = min(max(y0, 0), 255), yc1 = min(max(y1, 0), 255);
            float vx0 = (x0 >= 0 && x0 < 256) ? 1.f : 0.f;
            float vx1 = (x1 >= 0 && x1 < 256) ? 1.f : 0.f;
            float vy0 = (y0 >= 0 && y0 < 256) ? 1.f : 0.f;
            float vy1 = (y1 >= 0 && y1 < 256) ? 1.f : 0.f;
            pixi[p][0] = yc0 * 256 + xc0; vm[p][0] = vx0 * vy0;
            pixi[p][1] = yc0 * 256 + xc1; vm[p][1] = vx1 * vy0;
            pixi[p][2] = yc1 * 256 + xc0; vm[p][2] = vx0 * vy1;
            pixi[p][3] = yc1 * 256 + xc1; vm[p][3] = vx1 * vy1;
        }

        // ---- gather 36 bf16 values (independent loads; compiler batches) ----
        unsigned short us[3][4][3];
        #pragma unroll
        for (int p = 0; p < 3; ++p) {
            const unsigned short* bp = pb + (size_t)p * 65536 * C_;
            #pragma unroll
            for (int j = 0; j < 4; ++j) {
                const unsigned short* a = bp + (size_t)pixi[p][j] * C_ + lane;
                us[p][j][0] = a[0];
                us[p][j][1] = a[64];
                us[p][j][2] = a[128];
            }
        }

        // ---- bilinear combine -> feat (LDS) + gradient combos (regs) ----
        float gxc[9], gyc[9];
        #pragma unroll
        for (int k = 0; k < 3; ++k) {
            float f = 0.f;
            #pragma unroll
            for (int p = 0; p < 3; ++p) {
                float g0 = bf2f(us[p][0][k]) * vm[p][0];
                float g1 = bf2f(us[p][1][k]) * vm[p][1];
                float g2 = bf2f(us[p][2][k]) * vm[p][2];
                float g3 = bf2f(us[p][3][k]) * vm[p][3];
                f += wx0[p] * wy0[p] * g0 + wx1[p] * wy0[p] * g1
                   + wx0[p] * wy1[p] * g2 + wx1[p] * wy1[p] * g3;
                gxc[p * 3 + k] = wy0[p] * (g1 - g0) + wy1[p] * (g3 - g2);
                gyc[p * 3 + k] = wx0[p] * (g2 - g0) + wx1[p] * (g3 - g1);
            }
            feat_s[lane + 64 * k] = f * (1.0f / 3.0f);
        }
        asm volatile("s_waitcnt lgkmcnt(0)" ::: "memory");

        // ---- MLP forward: lane == hidden unit ----
        #pragma unroll
        for (int l = 0; l < L_; ++l) {
            const float* w2l = &w2s[(l * HID_ + lane) * 5];
            float w20 = w2l[0], w21 = w2l[1], w22 = w2l[2], w23 = w2l[3];

            float z0 = b1r[l], z1 = 0.f;
            #pragma unroll
            for (int q = 0; q < 8; ++q) {
                float4 fv = *(const float4*)&feat_s[l * CPL_ + 4 * q];
                z0 = fmaf(fv.x, w1s[((l*CPL_ + 4*q + 0) << 6) + (lane ^ (((4*q + 0) & 31) << 1))], z0);
                z1 = fmaf(fv.y, w1s[((l*CPL_ + 4*q + 1) << 6) + (lane ^ (((4*q + 1) & 31) << 1))], z1);
                z0 = fmaf(fv.z, w1s[((l*CPL_ + 4*q + 2) << 6) + (lane ^ (((4*q + 2) & 31) << 1))], z0);
                z1 = fmaf(fv.w, w1s[((l*CPL_ + 4*q + 3) << 6) + (lane ^ (((4*q + 3) & 31) << 1))], z1);
            }
            float z  = z0 + z1;
            float e  = expf(-fabsf(z));
            float sp = fmaxf(z, 0.f) + log1pf(e);
            float sg = ((z > 0.f) ? 1.0f : e) / (1.0f + e);   // sigmoid(z)
            dz_s[l * HID_ + lane] = sg * w20;

            float o0 = sp * w20, o1 = sp * w21, o2 = sp * w22, o3 = sp * w23;
            float u  = (lane & 1) ? o1 : o0;
            float uw = (lane & 1) ? o0 : o1;
            u += __shfl_xor(uw, 1, 64);
            float v  = (lane & 1) ? o3 : o2;
            float vw = (lane & 1) ? o2 : o3;
            v += __shfl_xor(vw, 1, 64);
            float tt = (lane & 2) ? v : u;
            float tw = (lane & 2) ? u : v;
            tt += __shfl_xor(tw, 2, 64);
            tt += __shfl_xor(tt, 4, 64);
            tt += __shfl_xor(tt, 8, 64);
            tt += __shfl_xor(tt, 16, 64);
            tt += __shfl_xor(tt, 32, 64);
            if ((lane >> 2) == l)
                o_s[lane] = tt + b2r[l];
        }
        asm volatile("s_waitcnt lgkmcnt(0)" ::: "memory");

        // ---- dfeat from LDS w1 (b64 reads, XOR-deswizzle) ----
        float df[3];
        #pragma unroll
        for (int k = 0; k < 3; ++k) {
            const int cg = lane + 64 * k;
            const float* wr  = &w1s[cg << 6];
            const float* dzr = &dz_s[(cg >> 5) * HID_];
            float a0 = 0.f, a1 = 0.f;
            #pragma unroll
            for (int h2 = 0; h2 < 32; ++h2) {
                float2 wv = *(const float2*)&wr[(2 * h2) ^ Cx];
                float2 dv = *(const float2*)&dzr[2 * h2];
                a0 = fmaf(wv.x, dv.x, a0);
                a1 = fmaf(wv.y, dv.y, a1);
            }
            df[k] = a0 + a1;
        }

        // ---- gradient dots + wave reduction ----
        float ax[3] = {0.f, 0.f, 0.f};
        float ay[3] = {0.f, 0.f, 0.f};
        #pragma unroll
        for (int k = 0; k < 3; ++k)
            #pragma unroll
            for (int p = 0; p < 3; ++p) {
                ax[p] = fmaf(df[k], gxc[p * 3 + k], ax[p]);
                ay[p] = fmaf(df[k], gyc[p * 3 + k], ay[p]);
            }
        #pragma unroll
        for (int s = 1; s < 64; s <<= 1) {
            ax[0] += __shfl_xor(ax[0], s, 64);
            ax[1] += __shfl_xor(ax[1], s, 64);
            ax[2] += __shfl_xor(ax[2], s, 64);
            ay[0] += __shfl_xor(ay[0], s, 64);
            ay[1] += __shfl_xor(ay[1], s, 64);
            ay[2] += __shfl_xor(ay[2], s, 64);
        }
        const float F = 128.0f / 3.0f;
        float gcx = F * (ax[0] + ax[1]);
        float gcy = F * (ay[0] + ay[2]);
        float gcz = F * (ay[1] + ax[2]);

        // ---- epilogue ----
        float olev[L_][4];
        #pragma unroll
        for (int l = 0; l < L_; ++l) {
            float4 ov = *(const float4*)&o_s[4 * l];
            olev[l][0] = ov.x; olev[l][1] = ov.y;
            olev[l][2] = ov.z; olev[l][3] = ov.w;
        }

        float r    = sqrtf(cx * cx + cy * cy + cz * cz);
        float smpl = r - 0.5f;
        float delta = 0.f;
        #pragma unroll
        for (int l = 0; l < L_; ++l) delta += olev[l][0];
        float sdf = smpl + delta;

        float ls[L_], sigma = 0.f;
        #pragma unroll
        for (int l = 0; l < L_; ++l) {
            float s = olev[l][0] + smpl;
            ls[l] = (1.0f / (1.0f + expf(s / beta))) / beta;
            sigma += ls[l];
        }
        float inv = 1.0f / (sigma + 1e-8f);
        float sem[L_];
        #pragma unroll
        for (int l = 0; l < L_; ++l) sem[l] = ls[l] * inv;

        float r0 = 0.f, r1 = 0.f, r2 = 0.f;
        #pragma unroll
        for (int l = 0; l < L_; ++l) {
            r0 = fmaf(olev[l][1], sem[l], r0);
            r1 = fmaf(olev[l][2], sem[l], r1);
            r2 = fmaf(olev[l][3], sem[l], r2);
        }
        float rgb0 = (1.0f / (1.0f + expf(-r0))) * 1.002f - 0.001f;
        float rgb1 = (1.0f / (1.0f + expf(-r1))) * 1.002f - 0.001f;
        float rgb2 = (1.0f / (1.0f + expf(-r2))) * 1.002f - 0.001f;

        float rinv = 1.0f / (r + 1e-8f);
        if (lane < 17) {
            float v =
                (lane == 0)  ? sdf :
                (lane == 1)  ? sigma :
                (lane == 2)  ? rgb0 :
                (lane == 3)  ? rgb1 :
                (lane == 4)  ? rgb2 :
                (lane == 5)  ? sem[0] :
                (lane == 6)  ? sem[1] :
                (lane == 7)  ? sem[2] :
                (lane == 8)  ? sem[3] :
                (lane == 9)  ? sem[4] :
                (lane == 10) ? sem[5] :
                (lane == 11) ? gcx + cx * rinv :
                (lane == 12) ? gcy + cy * rinv :
                (lane == 13) ? gcz + cz * rinv :
                (lane == 14) ? gcx :
                (lane == 15) ? gcy : gcz;
            out[(size_t)(gw * 8 + i) * 17 + lane] = v;
        }
    }
}

// ---------------------------------------------------------------------------
// Fallback (no workspace): original 1-point/wave kernel, f32 plane reads.
// ---------------------------------------------------------------------------
__global__ __launch_bounds__(256, 4) void point_fallback(
    const float* __restrict__ planes_f32,          // (NP,C,HW) f32
    const float* __restrict__ coords,
    const float* __restrict__ w1,
    const float* __restrict__ b1,
    const float* __restrict__ w2,
    const float* __restrict__ b2,
    const float* __restrict__ betap,
    float* __restrict__ out)
{
    __shared__ __align__(16) float feat_s[4][C_];
    __shared__ __align__(16) float dz_s[4][L_ * HID_];
    __shared__ __align__(16) float o_s[4][24];

    const int wave  = threadIdx.x >> 6;
    const int lane  = threadIdx.x & 63;
    const int point = blockIdx.x * 4 + wave;
    const int n     = point >> 16;

    const float cx = coords[point * 3 + 0];
    const float cy = coords[point * 3 + 1];
    const float cz = coords[point * 3 + 2];

    const float pjx[3] = {cx, cx, cz};
    const float pjy[3] = {cy, cz, cy};

    float wx0[3], wx1[3], wy0[3], wy1[3];
    int   pixi[3][4];
    float vmk[3][4];
    #pragma unroll
    for (int p = 0; p < 3; ++p) {
        float px = (pjx[p] + 1.0f) * 128.0f - 0.5f;
        float py = (pjy[p] + 1.0f) * 128.0f - 0.5f;
        float x0f = floorf(px), y0f = floorf(py);
        wx1[p] = px - x0f; wx0[p] = 1.0f - wx1[p];
        wy1[p] = py - y0f; wy0[p] = 1.0f - wy1[p];
        int x0 = (int)x0f, y0 = (int)y0f;
        int x1 = x0 + 1,  y1 = y0 + 1;
        int xc0 = min(max(x0, 0), 255), xc1 = min(max(x1, 0), 255);
        int yc0 = min(max(y0, 0), 255), yc1 = min(max(y1, 0), 255);
        float vx0 = (x0 >= 0 && x0 < 256) ? 1.f : 0.f;
        float vx1 = (x1 >= 0 && x1 < 256) ? 1.f : 0.f;
        float vy0 = (y0 >= 0 && y0 < 256) ? 1.f : 0.f;
        float vy1 = (y1 >= 0 && y1 < 256) ? 1.f : 0.f;
        pixi[p][0] = yc0 * 256 + xc0; vmk[p][0] = vx0 * vy0;
        pixi[p][1] = yc0 * 256 + xc1; vmk[p][1] = vx1 * vy0;
        pixi[p][2] = yc1 * 256 + xc0; vmk[p][2] = vx0 * vy1;
        pixi[p][3] = yc1 * 256 + xc1; vmk[p][3] = vx1 * vy1;
    }

    float g[3][4][3];
    #pragma unroll
    for (int p = 0; p < 3; ++p)
        #pragma unroll
        for (int ij = 0; ij < 4; ++ij)
            #pragma unroll
            for (int k = 0; k < 3; ++k) {
                int Cc = lane + 64 * k;
                size_t a = ((size_t)((n * 3 + p) * C_ + Cc)) * 65536 + pixi[p][ij];
                g[p][ij][k] = planes_f32[a] * vmk[p][ij];
            }

    #pragma unroll
    for (int k = 0; k < 3; ++k) {
        float f = 0.f;
        #pragma unroll
        for (int p = 0; p < 3; ++p) {
            f += wx0[p] * wy0[p] * g[p][0][k] + wx1[p] * wy0[p] * g[p][1][k]
               + wx0[p] * wy1[p] * g[p][2][k] + wx1[p] * wy1[p] * g[p][3][k];
        }
        feat_s[wave][lane + 64 * k] = f * (1.0f / 3.0f);
    }
    asm volatile("s_waitcnt lgkmcnt(0)" ::: "memory");

    #pragma unroll
    for (int l = 0; l < L_; ++l) {
        float b1l = b1[l * HID_ + lane];
        const float* w2l = w2 + (l * HID_ + lane) * 5;
        float w20 = w2l[0], w21 = w2l[1], w22 = w2l[2], w23 = w2l[3];

        float z0 = b1l, z1 = 0.f;
        #pragma unroll
        for (int q = 0; q < 8; ++q) {
            float4 fv = *(const float4*)&feat_s[wave][l * CPL_ + 4 * q];
            z0 = fmaf(fv.x, w1[(l * CPL_ + 4 * q + 0) * HID_ + lane], z0);
            z1 = fmaf(fv.y, w1[(l * CPL_ + 4 * q + 1) * HID_ + lane], z1);
            z0 = fmaf(fv.z, w1[(l * CPL_ + 4 * q + 2) * HID_ + lane], z0);
            z1 = fmaf(fv.w, w1[(l * CPL_ + 4 * q + 3) * HID_ + lane], z1);
        }
        float z  = z0 + z1;
        float e  = expf(-fabsf(z));
        float sp = fmaxf(z, 0.f) + log1pf(e);
        float sg = ((z > 0.f) ? 1.0f : e) / (1.0f + e);
        dz_s[wave][l * HID_ + lane] = sg * w20;

        float o0 = sp * w20, o1 = sp * w21, o2 = sp * w22, o3 = sp * w23;
        float u  = (lane & 1) ? o1 : o0;
        float uw = (lane & 1) ? o0 : o1;
        u += __shfl_xor(uw, 1, 64);
        float v  = (lane & 1) ? o3 : o2;
        float vw = (lane & 1) ? o2 : o3;
        v += __shfl_xor(vw, 1, 64);
        float tt = (lane & 2) ? v : u;
        float tw = (lane & 2) ? u : v;
        tt += __shfl_xor(tw, 2, 64);
        tt += __shfl_xor(tt, 4, 64);
        tt += __shfl_xor(tt, 8, 64);
        tt += __shfl_xor(tt, 16, 64);
        tt += __shfl_xor(tt, 32, 64);
        if ((lane >> 2) == l)
            o_s[wave][lane] = tt + b2[l * 5 + (lane & 3)];
    }
    asm volatile("s_waitcnt lgkmcnt(0)" ::: "memory");

    float df[3];
    #pragma unroll
    for (int k = 0; k < 3; ++k) {
        int cg = lane + 64 * k;
        const float* w1r = w1 + cg * HID_;
        const float* dzr = &dz_s[wave][(cg >> 5) * HID_];
        float a0 = 0.f, a1 = 0.f;
        #pragma unroll
        for (int h4 = 0; h4 < 16; ++h4) {
            float4 wv = *(const float4*)(w1r + 4 * h4);
            float4 dv = *(const float4*)(dzr + 4 * h4);
            a0 = fmaf(wv.x, dv.x, a0);
            a1 = fmaf(wv.y, dv.y, a1);
            a0 = fmaf(wv.z, dv.z, a0);
            a1 = fmaf(wv.w, dv.w, a1);
        }
        df[k] = a0 + a1;
    }

    float ax[3] = {0.f, 0.f, 0.f};
    float ay[3] = {0.f, 0.f, 0.f};
    #pragma unroll
    for (int k = 0; k < 3; ++k)
        #pragma unroll
        for (int p = 0; p < 3; ++p) {
            ax[p] = fmaf(df[k], wy0[p] * (g[p][1][k] - g[p][0][k])
                               + wy1[p] * (g[p][3][k] - g[p][2][k]), ax[p]);
            ay[p] = fmaf(df[k], wx0[p] * (g[p][2][k] - g[p][0][k])
                               + wx1[p] * (g[p][3][k] - g[p][1][k]), ay[p]);
        }
    #pragma unroll
    for (int s = 1; s < 64; s <<= 1) {
        ax[0] += __shfl_xor(ax[0], s, 64);
        ax[1] += __shfl_xor(ax[1], s, 64);
        ax[2] += __shfl_xor(ax[2], s, 64);
        ay[0] += __shfl_xor(ay[0], s, 64);
        ay[1] += __shfl_xor(ay[1], s, 64);
        ay[2] += __shfl_xor(ay[2], s, 64);
    }
    const float F = 128.0f / 3.0f;
    float gcx = F * (ax[0] + ax[1]);
    float gcy = F * (ay[0] + ay[2]);
    float gcz = F * (ay[1] + ax[2]);

    const float beta = betap[0];
    float olev[L_][4];
    #pragma unroll
    for (int l = 0; l < L_; ++l) {
        float4 ov = *(const float4*)&o_s[wave][4 * l];
        olev[l][0] = ov.x; olev[l][1] = ov.y;
        olev[l][2] = ov.z; olev[l][3] = ov.w;
    }

    float r    = sqrtf(cx * cx + cy * cy + cz * cz);
    float smpl = r - 0.5f;
    float delta = 0.f;
    #pragma unroll
    for (int l = 0; l < L_; ++l) delta += olev[l][0];
    float sdf = smpl + delta;

    float ls[L_], sigma = 0.f;
    #pragma unroll
    for (int l = 0; l < L_; ++l) {
        float s = olev[l][0] + smpl;
        ls[l] = (1.0f / (1.0f + expf(s / beta))) / beta;
        sigma += ls[l];
    }
    float inv = 1.0f / (sigma + 1e-8f);
    float sem[L_];
    #pragma unroll
    for (int l = 0; l < L_; ++l) sem[l] = ls[l] * inv;

    float r0 = 0.f, r1 = 0.f, r2 = 0.f;
    #pragma unroll
    for (int l = 0; l < L_; ++l) {
        r0 = fmaf(olev[l][1], sem[l], r0);
        r1 = fmaf(olev[l][2], sem[l], r1);
        r2 = fmaf(olev[l][3], sem[l], r2);
    }
    float rgb0 = (1.0f / (1.0f + expf(-r0))) * 1.002f - 0.001f;
    float rgb1 = (1.0f / (1.0f + expf(-r1))) * 1.002f - 0.001f;
    float rgb2 = (1.0f / (1.0f + expf(-r2))) * 1.002f - 0.001f;

    float rinv = 1.0f / (r + 1e-8f);
    if (lane < 17) {
        float v =
            (lane == 0)  ? sdf :
            (lane == 1)  ? sigma :
            (lane == 2)  ? rgb0 :
            (lane == 3)  ? rgb1 :
            (lane == 4)  ? rgb2 :
            (lane == 5)  ? sem[0] :
            (lane == 6)  ? sem[1] :
            (lane == 7)  ? sem[2] :
            (lane == 8)  ? sem[3] :
            (lane == 9)  ? sem[4] :
            (lane == 10) ? sem[5] :
            (lane == 11) ? gcx + cx * rinv :
            (lane == 12) ? gcy + cy * rinv :
            (lane == 13) ? gcz + cz * rinv :
            (lane == 14) ? gcx :
            (lane == 15) ? gcy : gcz;
        out[(size_t)point * 17 + lane] = v;
    }
}

extern "C" void kernel_launch(void* const* d_in, const int* in_sizes, int n_in,
                              void* d_out, int out_size, void* d_ws, size_t ws_size,
                              hipStream_t stream)
{
    const float* planes = (const float*)d_in[0];
    const float* coords = (const float*)d_in[1];
    const float* w1     = (const float*)d_in[2];
    const float* b1     = (const float*)d_in[3];
    const float* w2     = (const float*)d_in[4];
    const float* b2     = (const float*)d_in[5];
    const float* beta   = (const float*)d_in[6];
    float* out = (float*)d_out;

    const size_t need = (size_t)6 * 65536 * C_ * sizeof(unsigned short); // 151 MB
    const int shmem = 19616 * 4;   // 78464 B dynamic LDS for point2

    if (ws_size >= need) {
        static bool attr_done = false;
        if (!attr_done) {
            (void)hipFuncSetAttribute(reinterpret_cast<const void*>(&point2),
                                      hipFuncAttributeMaxDynamicSharedMemorySize,
                                      shmem);
            attr_done = true;
        }
        unsigned short* tp = (unsigned short*)d_ws;
        transpose_kernel<<<6 * 2048, 256, 0, stream>>>(planes, tp);
        point2<<<2048, 512, shmem, stream>>>(
            tp, coords, w1, b1, w2, b2, beta, out);
    } else {
        point_fallback<<<131072 / 4, 256, 0, stream>>>(
            planes, coords, w1, b1, w2, b2, beta, out);
    }
}

// Round 4
// 1009.173 us; speedup vs baseline: 3.7139x; 1.1494x over previous
//
#include <hip/hip_runtime.h>
#include <math.h>

#define P_   3
#define L_   6
#define CPL_ 32
#define C_   192
#define HID_ 64

__device__ __forceinline__ float bf2f(unsigned short u) {
    return __uint_as_float(((unsigned int)u) << 16);
}
// fast native transcendentals (v_exp_f32 / v_log_f32 / v_rcp_f32)
__device__ __forceinline__ float fexp(float x)  { return __expf(x); }
__device__ __forceinline__ float frcp(float x)  { return __builtin_amdgcn_rcpf(x); }
__device__ __forceinline__ float flog1p(float e){ return __logf(1.0f + e); }

// ---------------------------------------------------------------------------
// Transpose planes (N,P,C,256,256) f32  ->  (N,P,65536,C) bf16
// v4: phase-2 widened to uint4 stores (2x b128 LDS reads, 16B global store)
// ---------------------------------------------------------------------------
__global__ __launch_bounds__(256) void transpose_kernel(
    const float* __restrict__ in, unsigned short* __restrict__ out)
{
    __shared__ __align__(16) float tile[32][196];
    const int np   = blockIdx.x >> 11;
    const int pix0 = (blockIdx.x & 2047) << 5;
    const float* src = in + (size_t)np * C_ * 65536;
    uint4* dst4 = (uint4*)(out + (size_t)np * 65536 * C_);
    const int t = threadIdx.x;

    #pragma unroll
    for (int it = 0; it < 6; ++it) {
        int idx = it * 256 + t;               // 0..1535
        int Cc  = idx >> 3;                   // 0..191
        int pq  = idx & 7;                    // 0..7 -> px = 4*pq..4*pq+3
        float4 fv = *(const float4*)&src[(size_t)Cc * 65536 + pix0 + 4 * pq];
        tile[4 * pq + 0][Cc] = fv.x;
        tile[4 * pq + 1][Cc] = fv.y;
        tile[4 * pq + 2][Cc] = fv.z;
        tile[4 * pq + 3][Cc] = fv.w;
    }
    __syncthreads();
    #pragma unroll
    for (int it = 0; it < 3; ++it) {
        int idx = it * 256 + t;               // 0..767
        int c8  = idx % 24;                   // 24 chunks of 8 channels
        int px  = idx / 24;                   // 0..31
        float4 a = *(const float4*)&tile[px][8 * c8];
        float4 b = *(const float4*)&tile[px][8 * c8 + 4];
        unsigned int u0 = __float_as_uint(a.x), u1 = __float_as_uint(a.y);
        unsigned int u2 = __float_as_uint(a.z), u3 = __float_as_uint(a.w);
        unsigned int u4 = __float_as_uint(b.x), u5 = __float_as_uint(b.y);
        unsigned int u6 = __float_as_uint(b.z), u7 = __float_as_uint(b.w);
        u0 = (u0 + 0x7fffu + ((u0 >> 16) & 1)) >> 16;
        u1 = (u1 + 0x7fffu + ((u1 >> 16) & 1)) >> 16;
        u2 = (u2 + 0x7fffu + ((u2 >> 16) & 1)) >> 16;
        u3 = (u3 + 0x7fffu + ((u3 >> 16) & 1)) >> 16;
        u4 = (u4 + 0x7fffu + ((u4 >> 16) & 1)) >> 16;
        u5 = (u5 + 0x7fffu + ((u5 >> 16) & 1)) >> 16;
        u6 = (u6 + 0x7fffu + ((u6 >> 16) & 1)) >> 16;
        u7 = (u7 + 0x7fffu + ((u7 >> 16) & 1)) >> 16;
        uint4 pk;
        pk.x = u0 | (u1 << 16);
        pk.y = u2 | (u3 << 16);
        pk.z = u4 | (u5 << 16);
        pk.w = u6 | (u7 << 16);
        dst4[(size_t)(pix0 + px) * 24 + c8] = pk;
    }
}

// ---------------------------------------------------------------------------
// Persistent waves, 8 points/wave, weights LDS-resident.
// v4: native transcendentals (v_exp/v_log/v_rcp instead of libm expf/log1pf
// and IEEE divides — ~600 VALU instr/point of scaffolding removed), and the
// gradient reduction combines (ax0+ax1, ay0+ay2, ay1+ax2) BEFORE the
// butterfly: 3 values x 6 steps instead of 6 x 6, 9 fewer live VGPRs.
//
// LDS layout unchanged: 19616 floats = 78464 B -> 2 blocks/CU
// ---------------------------------------------------------------------------
__global__ __launch_bounds__(512)
__attribute__((amdgpu_waves_per_eu(2, 4))) void point2(
    const unsigned short* __restrict__ planes_bf,   // (NP,HW,C) bf16
    const float* __restrict__ coords,
    const float* __restrict__ w1,       // (L, CPL, HID)
    const float* __restrict__ b1,       // (L, HID)
    const float* __restrict__ w2,       // (L, HID, 5)
    const float* __restrict__ b2,       // (L, 5)
    const float* __restrict__ betap,
    float* __restrict__ out)            // (N*M, 17)
{
    extern __shared__ float sm[];
    float* w1s = sm;                 // 12288
    float* b1s = sm + 12288;         // 384
    float* w2s = sm + 12672;         // 1920
    float* b2s = sm + 14592;         // 32
    float* cds = sm + 14624;         // 192
    float* pwv = sm + 14816;         // 8 * 600

    const int tid  = threadIdx.x;
    const int wave = tid >> 6;
    const int lane = tid & 63;
    float* feat_s = pwv + wave * 600;
    float* dz_s   = feat_s + 192;
    float* o_s    = dz_s + 384;

    // ---- stage weights + coords into LDS (once per block) ----
    #pragma unroll
    for (int it = 0; it < 24; ++it) {
        int idx = it * 512 + tid;            // 0..12287
        int cg = idx >> 6, h = idx & 63;
        w1s[cg * 64 + (h ^ ((cg & 31) << 1))] = w1[idx];
    }
    if (tid < 384) b1s[tid] = b1[tid];
    #pragma unroll
    for (int it = 0; it < 4; ++it) {
        int idx = it * 512 + tid;
        if (idx < 1920) w2s[idx] = w2[idx];
    }
    if (tid < 30)  b2s[tid] = b2[tid];
    if (tid < 192) cds[tid] = coords[(size_t)blockIdx.x * 192 + tid];
    __syncthreads();

    // ---- per-lane weight registers (reused by all 8 points) ----
    float b1r[L_], b2r[L_];
    #pragma unroll
    for (int l = 0; l < L_; ++l) {
        b1r[l] = b1s[l * HID_ + lane];
        b2r[l] = b2s[l * 5 + (lane & 3)];
    }

    const float rbeta = frcp(betap[0]);            // 1/beta
    const int gw = blockIdx.x * 8 + wave;          // global wave id, 8 pts each
    const int n  = blockIdx.x >> 10;               // batch index (uniform/block)
    const unsigned short* pb = planes_bf + (size_t)n * 3 * 65536 * C_;
    const int Cx = (lane & 31) << 1;               // dfeat de-swizzle

    #pragma unroll 1
    for (int i = 0; i < 8; ++i) {
        const int pt3 = (wave * 8 + i) * 3;
        const float cx = cds[pt3 + 0];
        const float cy = cds[pt3 + 1];
        const float cz = cds[pt3 + 2];
        const float pjx[3] = {cx, cx, cz};
        const float pjy[3] = {cy, cz, cy};

        // ---- bilinear setup ----
        float wx0[3], wx1[3], wy0[3], wy1[3], vm[3][4];
        int   pixi[3][4];
        #pragma unroll
        for (int p = 0; p < 3; ++p) {
            float px = (pjx[p] + 1.0f) * 128.0f - 0.5f;
            float py = (pjy[p] + 1.0f) * 128.0f - 0.5f;
            float x0f = floorf(px), y0f = floorf(py);
            wx1[p] = px - x0f; wx0[p] = 1.0f - wx1[p];
            wy1[p] = py - y0f; wy0[p] = 1.0f - wy1[p];
            int x0 = (int)x0f, y0 = (int)y0f;
            int x1 = x0 + 1,  y1 = y0 + 1;
            int xc0 = min(max(x0, 0), 255), xc1 = min(max(x1, 0), 255);
            int yc0 = min(max(y0, 0), 255), yc1 = min(max(y1, 0), 255);
            float vx0 = (x0 >= 0 && x0 < 256) ? 1.f : 0.f;
            float vx1 = (x1 >= 0 && x1 < 256) ? 1.f : 0.f;
            float vy0 = (y0 >= 0 && y0 < 256) ? 1.f : 0.f;
            float vy1 = (y1 >= 0 && y1 < 256) ? 1.f : 0.f;
            pixi[p][0] = yc0 * 256 + xc0; vm[p][0] = vx0 * vy0;
            pixi[p][1] = yc0 * 256 + xc1; vm[p][1] = vx1 * vy0;
            pixi[p][2] = yc1 * 256 + xc0; vm[p][2] = vx0 * vy1;
            pixi[p][3] = yc1 * 256 + xc1; vm[p][3] = vx1 * vy1;
        }

        // ---- gather 36 bf16 values ----
        unsigned short us[3][4][3];
        #pragma unroll
        for (int p = 0; p < 3; ++p) {
            const unsigned short* bp = pb + (size_t)p * 65536 * C_;
            #pragma unroll
            for (int j = 0; j < 4; ++j) {
                const unsigned short* a = bp + (size_t)pixi[p][j] * C_ + lane;
                us[p][j][0] = a[0];
                us[p][j][1] = a[64];
                us[p][j][2] = a[128];
            }
        }

        // ---- bilinear combine -> feat (LDS) + pre-combined grad combos ----
        // gx needs plane0.x+plane1.x; gy needs plane0.y+plane2.y;
        // gz needs plane1.y+plane2.x  (combined BEFORE lane reduction)
        float gxS[3], gyS[3], gzS[3];
        #pragma unroll
        for (int k = 0; k < 3; ++k) {
            float f = 0.f;
            float gxc[3], gyc[3];
            #pragma unroll
            for (int p = 0; p < 3; ++p) {
                float g0 = bf2f(us[p][0][k]) * vm[p][0];
                float g1 = bf2f(us[p][1][k]) * vm[p][1];
                float g2 = bf2f(us[p][2][k]) * vm[p][2];
                float g3 = bf2f(us[p][3][k]) * vm[p][3];
                f += wx0[p] * wy0[p] * g0 + wx1[p] * wy0[p] * g1
                   + wx0[p] * wy1[p] * g2 + wx1[p] * wy1[p] * g3;
                gxc[p] = wy0[p] * (g1 - g0) + wy1[p] * (g3 - g2);
                gyc[p] = wx0[p] * (g2 - g0) + wx1[p] * (g3 - g1);
            }
            gxS[k] = gxc[0] + gxc[1];
            gyS[k] = gyc[0] + gyc[2];
            gzS[k] = gyc[1] + gxc[2];
            feat_s[lane + 64 * k] = f * (1.0f / 3.0f);
        }
        asm volatile("s_waitcnt lgkmcnt(0)" ::: "memory");

        // ---- MLP forward: lane == hidden unit ----
        #pragma unroll
        for (int l = 0; l < L_; ++l) {
            const float* w2l = &w2s[(l * HID_ + lane) * 5];
            float w20 = w2l[0], w21 = w2l[1], w22 = w2l[2], w23 = w2l[3];

            float z0 = b1r[l], z1 = 0.f;
            #pragma unroll
            for (int q = 0; q < 8; ++q) {
                float4 fv = *(const float4*)&feat_s[l * CPL_ + 4 * q];
                z0 = fmaf(fv.x, w1s[((l*CPL_ + 4*q + 0) << 6) + (lane ^ (((4*q + 0) & 31) << 1))], z0);
                z1 = fmaf(fv.y, w1s[((l*CPL_ + 4*q + 1) << 6) + (lane ^ (((4*q + 1) & 31) << 1))], z1);
                z0 = fmaf(fv.z, w1s[((l*CPL_ + 4*q + 2) << 6) + (lane ^ (((4*q + 2) & 31) << 1))], z0);
                z1 = fmaf(fv.w, w1s[((l*CPL_ + 4*q + 3) << 6) + (lane ^ (((4*q + 3) & 31) << 1))], z1);
            }
            float z  = z0 + z1;
            float e  = fexp(-fabsf(z));
            float sp = fmaxf(z, 0.f) + flog1p(e);
            float d  = frcp(1.0f + e);
            float sg = ((z > 0.f) ? 1.0f : e) * d;   // sigmoid(z)
            dz_s[l * HID_ + lane] = sg * w20;

            float o0 = sp * w20, o1 = sp * w21, o2 = sp * w22, o3 = sp * w23;
            float u  = (lane & 1) ? o1 : o0;
            float uw = (lane & 1) ? o0 : o1;
            u += __shfl_xor(uw, 1, 64);
            float v  = (lane & 1) ? o3 : o2;
            float vw = (lane & 1) ? o2 : o3;
            v += __shfl_xor(vw, 1, 64);
            float tt = (lane & 2) ? v : u;
            float tw = (lane & 2) ? u : v;
            tt += __shfl_xor(tw, 2, 64);
            tt += __shfl_xor(tt, 4, 64);
            tt += __shfl_xor(tt, 8, 64);
            tt += __shfl_xor(tt, 16, 64);
            tt += __shfl_xor(tt, 32, 64);
            if ((lane >> 2) == l)
                o_s[lane] = tt + b2r[l];
        }
        asm volatile("s_waitcnt lgkmcnt(0)" ::: "memory");

        // ---- dfeat from LDS w1 (b64 reads, XOR-deswizzle) ----
        float df[3];
        #pragma unroll
        for (int k = 0; k < 3; ++k) {
            const int cg = lane + 64 * k;
            const float* wr  = &w1s[cg << 6];
            const float* dzr = &dz_s[(cg >> 5) * HID_];
            float a0 = 0.f, a1 = 0.f;
            #pragma unroll
            for (int h2 = 0; h2 < 32; ++h2) {
                float2 wv = *(const float2*)&wr[(2 * h2) ^ Cx];
                float2 dv = *(const float2*)&dzr[2 * h2];
                a0 = fmaf(wv.x, dv.x, a0);
                a1 = fmaf(wv.y, dv.y, a1);
            }
            df[k] = a0 + a1;
        }

        // ---- gradient dots (pre-combined) + 3-value wave reduction ----
        float gx = 0.f, gy = 0.f, gz = 0.f;
        #pragma unroll
        for (int k = 0; k < 3; ++k) {
            gx = fmaf(df[k], gxS[k], gx);
            gy = fmaf(df[k], gyS[k], gy);
            gz = fmaf(df[k], gzS[k], gz);
        }
        #pragma unroll
        for (int s = 1; s < 64; s <<= 1) {
            gx += __shfl_xor(gx, s, 64);
            gy += __shfl_xor(gy, s, 64);
            gz += __shfl_xor(gz, s, 64);
        }
        const float F = 128.0f / 3.0f;
        float gcx = F * gx;
        float gcy = F * gy;
        float gcz = F * gz;

        // ---- epilogue ----
        float olev[L_][4];
        #pragma unroll
        for (int l = 0; l < L_; ++l) {
            float4 ov = *(const float4*)&o_s[4 * l];
            olev[l][0] = ov.x; olev[l][1] = ov.y;
            olev[l][2] = ov.z; olev[l][3] = ov.w;
        }

        float r    = sqrtf(cx * cx + cy * cy + cz * cz);
        float smpl = r - 0.5f;
        float delta = 0.f;
        #pragma unroll
        for (int l = 0; l < L_; ++l) delta += olev[l][0];
        float sdf = smpl + delta;

        float ls[L_], sigma = 0.f;
        #pragma unroll
        for (int l = 0; l < L_; ++l) {
            float s = olev[l][0] + smpl;
            ls[l] = frcp(1.0f + fexp(s * rbeta)) * rbeta;
            sigma += ls[l];
        }
        float inv = frcp(sigma + 1e-8f);
        float sem[L_];
        #pragma unroll
        for (int l = 0; l < L_; ++l) sem[l] = ls[l] * inv;

        float r0 = 0.f, r1 = 0.f, r2 = 0.f;
        #pragma unroll
        for (int l = 0; l < L_; ++l) {
            r0 = fmaf(olev[l][1], sem[l], r0);
            r1 = fmaf(olev[l][2], sem[l], r1);
            r2 = fmaf(olev[l][3], sem[l], r2);
        }
        float rgb0 = frcp(1.0f + fexp(-r0)) * 1.002f - 0.001f;
        float rgb1 = frcp(1.0f + fexp(-r1)) * 1.002f - 0.001f;
        float rgb2 = frcp(1.0f + fexp(-r2)) * 1.002f - 0.001f;

        float rinv = frcp(r + 1e-8f);
        if (lane < 17) {
            float v =
                (lane == 0)  ? sdf :
                (lane == 1)  ? sigma :
                (lane == 2)  ? rgb0 :
                (lane == 3)  ? rgb1 :
                (lane == 4)  ? rgb2 :
                (lane == 5)  ? sem[0] :
                (lane == 6)  ? sem[1] :
                (lane == 7)  ? sem[2] :
                (lane == 8)  ? sem[3] :
                (lane == 9)  ? sem[4] :
                (lane == 10) ? sem[5] :
                (lane == 11) ? gcx + cx * rinv :
                (lane == 12) ? gcy + cy * rinv :
                (lane == 13) ? gcz + cz * rinv :
                (lane == 14) ? gcx :
                (lane == 15) ? gcy : gcz;
            out[(size_t)(gw * 8 + i) * 17 + lane] = v;
        }
    }
}

// ---------------------------------------------------------------------------
// Fallback (no workspace): original 1-point/wave kernel, f32 plane reads.
// ---------------------------------------------------------------------------
__global__ __launch_bounds__(256, 4) void point_fallback(
    const float* __restrict__ planes_f32,          // (NP,C,HW) f32
    const float* __restrict__ coords,
    const float* __restrict__ w1,
    const float* __restrict__ b1,
    const float* __restrict__ w2,
    const float* __restrict__ b2,
    const float* __restrict__ betap,
    float* __restrict__ out)
{
    __shared__ __align__(16) float feat_s[4][C_];
    __shared__ __align__(16) float dz_s[4][L_ * HID_];
    __shared__ __align__(16) float o_s[4][24];

    const int wave  = threadIdx.x >> 6;
    const int lane  = threadIdx.x & 63;
    const int point = blockIdx.x * 4 + wave;
    const int n     = point >> 16;

    const float cx = coords[point * 3 + 0];
    const float cy = coords[point * 3 + 1];
    const float cz = coords[point * 3 + 2];

    const float pjx[3] = {cx, cx, cz};
    const float pjy[3] = {cy, cz, cy};

    float wx0[3], wx1[3], wy0[3], wy1[3];
    int   pixi[3][4];
    float vmk[3][4];
    #pragma unroll
    for (int p = 0; p < 3; ++p) {
        float px = (pjx[p] + 1.0f) * 128.0f - 0.5f;
        float py = (pjy[p] + 1.0f) * 128.0f - 0.5f;
        float x0f = floorf(px), y0f = floorf(py);
        wx1[p] = px - x0f; wx0[p] = 1.0f - wx1[p];
        wy1[p] = py - y0f; wy0[p] = 1.0f - wy1[p];
        int x0 = (int)x0f, y0 = (int)y0f;
        int x1 = x0 + 1,  y1 = y0 + 1;
        int xc0 = min(max(x0, 0), 255), xc1 = min(max(x1, 0), 255);
        int yc0 = min(max(y0, 0), 255), yc1 = min(max(y1, 0), 255);
        float vx0 = (x0 >= 0 && x0 < 256) ? 1.f : 0.f;
        float vx1 = (x1 >= 0 && x1 < 256) ? 1.f : 0.f;
        float vy0 = (y0 >= 0 && y0 < 256) ? 1.f : 0.f;
        float vy1 = (y1 >= 0 && y1 < 256) ? 1.f : 0.f;
        pixi[p][0] = yc0 * 256 + xc0; vmk[p][0] = vx0 * vy0;
        pixi[p][1] = yc0 * 256 + xc1; vmk[p][1] = vx1 * vy0;
        pixi[p][2] = yc1 * 256 + xc0; vmk[p][2] = vx0 * vy1;
        pixi[p][3] = yc1 * 256 + xc1; vmk[p][3] = vx1 * vy1;
    }

    float g[3][4][3];
    #pragma unroll
    for (int p = 0; p < 3; ++p)
        #pragma unroll
        for (int ij = 0; ij < 4; ++ij)
            #pragma unroll
            for (int k = 0; k < 3; ++k) {
                int Cc = lane + 64 * k;
                size_t a = ((size_t)((n * 3 + p) * C_ + Cc)) * 65536 + pixi[p][ij];
                g[p][ij][k] = planes_f32[a] * vmk[p][ij];
            }

    #pragma unroll
    for (int k = 0; k < 3; ++k) {
        float f = 0.f;
        #pragma unroll
        for (int p = 0; p < 3; ++p) {
            f += wx0[p] * wy0[p] * g[p][0][k] + wx1[p] * wy0[p] * g[p][1][k]
               + wx0[p] * wy1[p] * g[p][2][k] + wx1[p] * wy1[p] * g[p][3][k];
        }
        feat_s[wave][lane + 64 * k] = f * (1.0f / 3.0f);
    }
    asm volatile("s_waitcnt lgkmcnt(0)" ::: "memory");

    #pragma unroll
    for (int l = 0; l < L_; ++l) {
        float b1l = b1[l * HID_ + lane];
        const float* w2l = w2 + (l * HID_ + lane) * 5;
        float w20 = w2l[0], w21 = w2l[1], w22 = w2l[2], w23 = w2l[3];

        float z0 = b1l, z1 = 0.f;
        #pragma unroll
        for (int q = 0; q < 8; ++q) {
            float4 fv = *(const float4*)&feat_s[wave][l * CPL_ + 4 * q];
            z0 = fmaf(fv.x, w1[(l * CPL_ + 4 * q + 0) * HID_ + lane], z0);
            z1 = fmaf(fv.y, w1[(l * CPL_ + 4 * q + 1) * HID_ + lane], z1);
            z0 = fmaf(fv.z, w1[(l * CPL_ + 4 * q + 2) * HID_ + lane], z0);
            z1 = fmaf(fv.w, w1[(l * CPL_ + 4 * q + 3) * HID_ + lane], z1);
        }
        float z  = z0 + z1;
        float e  = expf(-fabsf(z));
        float sp = fmaxf(z, 0.f) + log1pf(e);
        float sg = ((z > 0.f) ? 1.0f : e) / (1.0f + e);
        dz_s[wave][l * HID_ + lane] = sg * w20;

        float o0 = sp * w20, o1 = sp * w21, o2 = sp * w22, o3 = sp * w23;
        float u  = (lane & 1) ? o1 : o0;
        float uw = (lane & 1) ? o0 : o1;
        u += __shfl_xor(uw, 1, 64);
        float v  = (lane & 1) ? o3 : o2;
        float vw = (lane & 1) ? o2 : o3;
        v += __shfl_xor(vw, 1, 64);
        float tt = (lane & 2) ? v : u;
        float tw = (lane & 2) ? u : v;
        tt += __shfl_xor(tw, 2, 64);
        tt += __shfl_xor(tt, 4, 64);
        tt += __shfl_xor(tt, 8, 64);
        tt += __shfl_xor(tt, 16, 64);
        tt += __shfl_xor(tt, 32, 64);
        if ((lane >> 2) == l)
            o_s[wave][lane] = tt + b2[l * 5 + (lane & 3)];
    }
    asm volatile("s_waitcnt lgkmcnt(0)" ::: "memory");

    float df[3];
    #pragma unroll
    for (int k = 0; k < 3; ++k) {
        int cg = lane + 64 * k;
        const float* w1r = w1 + cg * HID_;
        const float* dzr = &dz_s[wave][(cg >> 5) * HID_];
        float a0 = 0.f, a1 = 0.f;
        #pragma unroll
        for (int h4 = 0; h4 < 16; ++h4) {
            float4 wv = *(const float4*)(w1r + 4 * h4);
            float4 dv = *(const float4*)(dzr + 4 * h4);
            a0 = fmaf(wv.x, dv.x, a0);
            a1 = fmaf(wv.y, dv.y, a1);
            a0 = fmaf(wv.z, dv.z, a0);
            a1 = fmaf(wv.w, dv.w, a1);
        }
        df[k] = a0 + a1;
    }

    float ax[3] = {0.f, 0.f, 0.f};
    float ay[3] = {0.f, 0.f, 0.f};
    #pragma unroll
    for (int k = 0; k < 3; ++k)
        #pragma unroll
        for (int p = 0; p < 3; ++p) {
            ax[p] = fmaf(df[k], wy0[p] * (g[p][1][k] - g[p][0][k])
                               + wy1[p] * (g[p][3][k] - g[p][2][k]), ax[p]);
            ay[p] = fmaf(df[k], wx0[p] * (g[p][2][k] - g[p][0][k])
                               + wx1[p] * (g[p][3][k] - g[p][1][k]), ay[p]);
        }
    #pragma unroll
    for (int s = 1; s < 64; s <<= 1) {
        ax[0] += __shfl_xor(ax[0], s, 64);
        ax[1] += __shfl_xor(ax[1], s, 64);
        ax[2] += __shfl_xor(ax[2], s, 64);
        ay[0] += __shfl_xor(ay[0], s, 64);
        ay[1] += __shfl_xor(ay[1], s, 64);
        ay[2] += __shfl_xor(ay[2], s, 64);
    }
    const float F = 128.0f / 3.0f;
    float gcx = F * (ax[0] + ax[1]);
    float gcy = F * (ay[0] + ay[2]);
    float gcz = F * (ay[1] + ax[2]);

    const float beta = betap[0];
    float olev[L_][4];
    #pragma unroll
    for (int l = 0; l < L_; ++l) {
        float4 ov = *(const float4*)&o_s[wave][4 * l];
        olev[l][0] = ov.x; olev[l][1] = ov.y;
        olev[l][2] = ov.z; olev[l][3] = ov.w;
    }

    float r    = sqrtf(cx * cx + cy * cy + cz * cz);
    float smpl = r - 0.5f;
    float delta = 0.f;
    #pragma unroll
    for (int l = 0; l < L_; ++l) delta += olev[l][0];
    float sdf = smpl + delta;

    float ls[L_], sigma = 0.f;
    #pragma unroll
    for (int l = 0; l < L_; ++l) {
        float s = olev[l][0] + smpl;
        ls[l] = (1.0f / (1.0f + expf(s / beta))) / beta;
        sigma += ls[l];
    }
    float inv = 1.0f / (sigma + 1e-8f);
    float sem[L_];
    #pragma unroll
    for (int l = 0; l < L_; ++l) sem[l] = ls[l] * inv;

    float r0 = 0.f, r1 = 0.f, r2 = 0.f;
    #pragma unroll
    for (int l = 0; l < L_; ++l) {
        r0 = fmaf(olev[l][1], sem[l], r0);
        r1 = fmaf(olev[l][2], sem[l], r1);
        r2 = fmaf(olev[l][3], sem[l], r2);
    }
    float rgb0 = (1.0f / (1.0f + expf(-r0))) * 1.002f - 0.001f;
    float rgb1 = (1.0f / (1.0f + expf(-r1))) * 1.002f - 0.001f;
    float rgb2 = (1.0f / (1.0f + expf(-r2))) * 1.002f - 0.001f;

    float rinv = 1.0f / (r + 1e-8f);
    if (lane < 17) {
        float v =
            (lane == 0)  ? sdf :
            (lane == 1)  ? sigma :
            (lane == 2)  ? rgb0 :
            (lane == 3)  ? rgb1 :
            (lane == 4)  ? rgb2 :
            (lane == 5)  ? sem[0] :
            (lane == 6)  ? sem[1] :
            (lane == 7)  ? sem[2] :
            (lane == 8)  ? sem[3] :
            (lane == 9)  ? sem[4] :
            (lane == 10) ? sem[5] :
            (lane == 11) ? gcx + cx * rinv :
            (lane == 12) ? gcy + cy * rinv :
            (lane == 13) ? gcz + cz * rinv :
            (lane == 14) ? gcx :
            (lane == 15) ? gcy : gcz;
        out[(size_t)point * 17 + lane] = v;
    }
}

extern "C" void kernel_launch(void* const* d_in, const int* in_sizes, int n_in,
                              void* d_out, int out_size, void* d_ws, size_t ws_size,
                              hipStream_t stream)
{
    const float* planes = (const float*)d_in[0];
    const float* coords = (const float*)d_in[1];
    const float* w1     = (const float*)d_in[2];
    const float* b1     = (const float*)d_in[3];
    const float* w2     = (const float*)d_in[4];
    const float* b2     = (const float*)d_in[5];
    const float* beta   = (const float*)d_in[6];
    float* out = (float*)d_out;

    const size_t need = (size_t)6 * 65536 * C_ * sizeof(unsigned short); // 151 MB
    const int shmem = 19616 * 4;   // 78464 B dynamic LDS for point2

    if (ws_size >= need) {
        static bool attr_done = false;
        if (!attr_done) {
            (void)hipFuncSetAttribute(reinterpret_cast<const void*>(&point2),
                                      hipFuncAttributeMaxDynamicSharedMemorySize,
                                      shmem);
            attr_done = true;
        }
        unsigned short* tp = (unsigned short*)d_ws;
        transpose_kernel<<<6 * 2048, 256, 0, stream>>>(planes, tp);
        point2<<<2048, 512, shmem, stream>>>(
            tp, coords, w1, b1, w2, b2, beta, out);
    } else {
        point_fallback<<<131072 / 4, 256, 0, stream>>>(
            planes, coords, w1, b1, w2, b2, beta, out);
    }
}

// Round 5
// 836.151 us; speedup vs baseline: 4.4824x; 1.2069x over previous
//
#include <hip/hip_runtime.h>
#include <math.h>

#define P_   3
#define L_   6
#define CPL_ 32
#define C_   192
#define HID_ 64

__device__ __forceinline__ float bf2f(unsigned short u) {
    return __uint_as_float(((unsigned int)u) << 16);
}
__device__ __forceinline__ unsigned short f2bf(float x) {
    unsigned int u = __float_as_uint(x);
    u = (u + 0x7fffu + ((u >> 16) & 1)) >> 16;
    return (unsigned short)u;
}
// fast native transcendentals (v_exp_f32 / v_log_f32 / v_rcp_f32)
__device__ __forceinline__ float fexp(float x)  { return __expf(x); }
__device__ __forceinline__ float frcp(float x)  { return __builtin_amdgcn_rcpf(x); }
__device__ __forceinline__ float flog1p(float e){ return __logf(1.0f + e); }

// ---------------------------------------------------------------------------
// Transpose planes (N,P,C,256,256) f32  ->  (N,P,65536,C) bf16
// v5: convert in phase 1; u32 tile with ODD stride 97 (bank-conflict-free
// b16 writes, ~2-way b32 reads); phase 2 = pure copy, coalesced uint4 stores.
// Old phase-2 b128 reads were ~6-way conflicted (8-word stride, 24 chunks).
// ---------------------------------------------------------------------------
__global__ __launch_bounds__(256) void transpose_kernel(
    const float* __restrict__ in, unsigned short* __restrict__ out)
{
    __shared__ unsigned int tile32[32 * 97 + 4];   // [px][ch/2], stride 97 u32
    const int np   = blockIdx.x >> 11;
    const int pix0 = (blockIdx.x & 2047) << 5;
    const float* src = in + (size_t)np * C_ * 65536;
    uint4* dst4 = (uint4*)(out + (size_t)np * 65536 * C_);
    const int t = threadIdx.x;
    unsigned short* tp = (unsigned short*)tile32;  // halfword stride 194

    #pragma unroll
    for (int it = 0; it < 6; ++it) {
        int idx = it * 256 + t;               // 0..1535
        int Cc  = idx >> 3;                   // 0..191
        int pq  = idx & 7;                    // px = 4*pq..4*pq+3
        float4 fv = *(const float4*)&src[(size_t)Cc * 65536 + pix0 + 4 * pq];
        tp[(4 * pq + 0) * 194 + Cc] = f2bf(fv.x);
        tp[(4 * pq + 1) * 194 + Cc] = f2bf(fv.y);
        tp[(4 * pq + 2) * 194 + Cc] = f2bf(fv.z);
        tp[(4 * pq + 3) * 194 + Cc] = f2bf(fv.w);
    }
    __syncthreads();
    #pragma unroll
    for (int it = 0; it < 3; ++it) {
        int idx = it * 256 + t;               // 0..767
        int c4  = idx % 24;                   // 24 chunks of 8 channels
        int px  = idx / 24;                   // 0..31
        const unsigned int* rp = tile32 + px * 97 + 4 * c4;
        uint4 pk;
        pk.x = rp[0]; pk.y = rp[1]; pk.z = rp[2]; pk.w = rp[3];
        dst4[(size_t)(pix0 + px) * 24 + c4] = pk;   // coalesced
    }
}

// ---------------------------------------------------------------------------
// Persistent waves, 8 points/wave, weights LDS-resident.
// v5: dfeat FOLDED INTO FORWARD LOOP — axl/ayl/azl accumulate
// w1[c,h]*g{x,y,z}S[c] on the same w1 value the fwd FMA just loaded; after
// the activation, gx += dz_l*axl. Deletes the dfeat block, dz_s, the w1
// XOR-swizzle, and one barrier (~40% of LDS cycles). o/grad reductions use
// a DEFERRED JOINT butterfly (9 values, strides shared) for 9-way ILP.
// w2 lives in 24 registers (frees 7.7KB LDS for the gS arrays).
//
// LDS (floats): w1s 12288 | b1s 384 | b2s 32 | cds 192 |
//   8 x (feat 192 + gxs 192 + gys 192 + gzs 192 + o 24 = 792)
// total 19232 floats = 76928 B -> 2 blocks/CU (16 waves, 4/SIMD)
// ---------------------------------------------------------------------------
__global__ __launch_bounds__(512)
__attribute__((amdgpu_waves_per_eu(4, 4))) void point2(
    const unsigned short* __restrict__ planes_bf,   // (NP,HW,C) bf16
    const float* __restrict__ coords,
    const float* __restrict__ w1,       // (L, CPL, HID)
    const float* __restrict__ b1,       // (L, HID)
    const float* __restrict__ w2,       // (L, HID, 5)
    const float* __restrict__ b2,       // (L, 5)
    const float* __restrict__ betap,
    float* __restrict__ out)            // (N*M, 17)
{
    extern __shared__ float sm[];
    float* w1s = sm;                 // 12288 (linear, no swizzle)
    float* b1s = sm + 12288;         // 384
    float* b2s = sm + 12672;         // 32
    float* cds = sm + 12704;         // 192
    float* pwv = sm + 12896;         // 8 * 792

    const int tid  = threadIdx.x;
    const int wave = tid >> 6;
    const int lane = tid & 63;
    float* feat_s = pwv + wave * 792;
    float* gxs    = feat_s + 192;
    float* gys    = gxs + 192;
    float* gzs    = gys + 192;
    float* o_s    = gzs + 192;       // 24

    // ---- stage weights + coords into LDS (once per block) ----
    #pragma unroll
    for (int it = 0; it < 6; ++it) {
        int idx = it * 512 + tid;            // 0..3071 float4s
        ((float4*)w1s)[idx] = ((const float4*)w1)[idx];
    }
    if (tid < 384) b1s[tid] = b1[tid];
    if (tid < 30)  b2s[tid] = b2[tid];
    if (tid < 192) cds[tid] = coords[(size_t)blockIdx.x * 192 + tid];
    __syncthreads();

    // ---- per-lane weight registers (reused by all 8 points) ----
    float b1r[L_], b2r[L_];
    float w2r0[L_], w2r1[L_], w2r2[L_], w2r3[L_];
    #pragma unroll
    for (int l = 0; l < L_; ++l) {
        b1r[l] = b1s[l * HID_ + lane];
        b2r[l] = b2s[l * 5 + (lane & 3)];
        const float* w2l = w2 + (size_t)(l * HID_ + lane) * 5;
        w2r0[l] = w2l[0]; w2r1[l] = w2l[1]; w2r2[l] = w2l[2]; w2r3[l] = w2l[3];
    }

    const float rbeta = frcp(betap[0]);            // 1/beta
    const int gw = blockIdx.x * 8 + wave;          // global wave id, 8 pts each
    const int n  = blockIdx.x >> 10;               // batch index (uniform/block)
    const unsigned short* pb = planes_bf + (size_t)n * 3 * 65536 * C_;

    #pragma unroll 1
    for (int i = 0; i < 8; ++i) {
        const int pt3 = (wave * 8 + i) * 3;
        const float cx = cds[pt3 + 0];
        const float cy = cds[pt3 + 1];
        const float cz = cds[pt3 + 2];
        const float pjx[3] = {cx, cx, cz};
        const float pjy[3] = {cy, cz, cy};

        // ---- bilinear setup ----
        float wx0[3], wx1[3], wy0[3], wy1[3], vm[3][4];
        int   pixi[3][4];
        #pragma unroll
        for (int p = 0; p < 3; ++p) {
            float px = (pjx[p] + 1.0f) * 128.0f - 0.5f;
            float py = (pjy[p] + 1.0f) * 128.0f - 0.5f;
            float x0f = floorf(px), y0f = floorf(py);
            wx1[p] = px - x0f; wx0[p] = 1.0f - wx1[p];
            wy1[p] = py - y0f; wy0[p] = 1.0f - wy1[p];
            int x0 = (int)x0f, y0 = (int)y0f;
            int x1 = x0 + 1,  y1 = y0 + 1;
            int xc0 = min(max(x0, 0), 255), xc1 = min(max(x1, 0), 255);
            int yc0 = min(max(y0, 0), 255), yc1 = min(max(y1, 0), 255);
            float vx0 = (x0 >= 0 && x0 < 256) ? 1.f : 0.f;
            float vx1 = (x1 >= 0 && x1 < 256) ? 1.f : 0.f;
            float vy0 = (y0 >= 0 && y0 < 256) ? 1.f : 0.f;
            float vy1 = (y1 >= 0 && y1 < 256) ? 1.f : 0.f;
            pixi[p][0] = yc0 * 256 + xc0; vm[p][0] = vx0 * vy0;
            pixi[p][1] = yc0 * 256 + xc1; vm[p][1] = vx1 * vy0;
            pixi[p][2] = yc1 * 256 + xc0; vm[p][2] = vx0 * vy1;
            pixi[p][3] = yc1 * 256 + xc1; vm[p][3] = vx1 * vy1;
        }

        // ---- gather 36 bf16 values ----
        unsigned short us[3][4][3];
        #pragma unroll
        for (int p = 0; p < 3; ++p) {
            const unsigned short* bp = pb + (size_t)p * 65536 * C_;
            #pragma unroll
            for (int j = 0; j < 4; ++j) {
                const unsigned short* a = bp + (size_t)pixi[p][j] * C_ + lane;
                us[p][j][0] = a[0];
                us[p][j][1] = a[64];
                us[p][j][2] = a[128];
            }
        }

        // ---- bilinear combine -> feat + gS (all to per-wave LDS) ----
        #pragma unroll
        for (int k = 0; k < 3; ++k) {
            float f = 0.f;
            float gxc[3], gyc[3];
            #pragma unroll
            for (int p = 0; p < 3; ++p) {
                float g0 = bf2f(us[p][0][k]) * vm[p][0];
                float g1 = bf2f(us[p][1][k]) * vm[p][1];
                float g2 = bf2f(us[p][2][k]) * vm[p][2];
                float g3 = bf2f(us[p][3][k]) * vm[p][3];
                f += wx0[p] * wy0[p] * g0 + wx1[p] * wy0[p] * g1
                   + wx0[p] * wy1[p] * g2 + wx1[p] * wy1[p] * g3;
                gxc[p] = wy0[p] * (g1 - g0) + wy1[p] * (g3 - g2);
                gyc[p] = wx0[p] * (g2 - g0) + wx1[p] * (g3 - g1);
            }
            feat_s[lane + 64 * k] = f * (1.0f / 3.0f);
            gxs[lane + 64 * k] = gxc[0] + gxc[1];
            gys[lane + 64 * k] = gyc[0] + gyc[2];
            gzs[lane + 64 * k] = gyc[1] + gxc[2];
        }
        asm volatile("s_waitcnt lgkmcnt(0)" ::: "memory");

        // ---- MLP forward + folded backward: lane == hidden unit ----
        float gx = 0.f, gy = 0.f, gz = 0.f;
        float tl[L_];
        #pragma unroll
        for (int l = 0; l < L_; ++l) {
            float z0 = b1r[l], z1 = 0.f;
            float axl = 0.f, ayl = 0.f, azl = 0.f;
            #pragma unroll
            for (int q = 0; q < 8; ++q) {
                const int c0 = l * CPL_ + 4 * q;
                float4 fv  = *(const float4*)&feat_s[c0];
                float4 gxv = *(const float4*)&gxs[c0];
                float4 gyv = *(const float4*)&gys[c0];
                float4 gzv = *(const float4*)&gzs[c0];
                float wA = w1s[((c0 + 0) << 6) + lane];
                float wB = w1s[((c0 + 1) << 6) + lane];
                float wC = w1s[((c0 + 2) << 6) + lane];
                float wD = w1s[((c0 + 3) << 6) + lane];
                z0 = fmaf(fv.x, wA, z0);
                z1 = fmaf(fv.y, wB, z1);
                z0 = fmaf(fv.z, wC, z0);
                z1 = fmaf(fv.w, wD, z1);
                axl = fmaf(wA, gxv.x, axl); axl = fmaf(wB, gxv.y, axl);
                axl = fmaf(wC, gxv.z, axl); axl = fmaf(wD, gxv.w, axl);
                ayl = fmaf(wA, gyv.x, ayl); ayl = fmaf(wB, gyv.y, ayl);
                ayl = fmaf(wC, gyv.z, ayl); ayl = fmaf(wD, gyv.w, ayl);
                azl = fmaf(wA, gzv.x, azl); azl = fmaf(wB, gzv.y, azl);
                azl = fmaf(wC, gzv.z, azl); azl = fmaf(wD, gzv.w, azl);
            }
            float z  = z0 + z1;
            float e  = fexp(-fabsf(z));
            float sp = fmaxf(z, 0.f) + flog1p(e);
            float d  = frcp(1.0f + e);
            float sg = ((z > 0.f) ? 1.0f : e) * d;   // sigmoid(z)
            float dzl = sg * w2r0[l];
            gx = fmaf(dzl, axl, gx);
            gy = fmaf(dzl, ayl, gy);
            gz = fmaf(dzl, azl, gz);

            float o0 = sp * w2r0[l], o1 = sp * w2r1[l];
            float o2 = sp * w2r2[l], o3 = sp * w2r3[l];
            // pack 4 -> 1 (value index = lane&3), butterfly deferred
            float u  = (lane & 1) ? o1 : o0;
            float uw = (lane & 1) ? o0 : o1;
            u += __shfl_xor(uw, 1, 64);
            float v  = (lane & 1) ? o3 : o2;
            float vw = (lane & 1) ? o2 : o3;
            v += __shfl_xor(vw, 1, 64);
            float tt = (lane & 2) ? v : u;
            float tw = (lane & 2) ? u : v;
            tt += __shfl_xor(tw, 2, 64);
            tl[l] = tt;
        }

        // ---- joint butterfly: gx/gy/gz (strides 1..32) + tl[6] (4..32) ----
        gx += __shfl_xor(gx, 1, 64);
        gy += __shfl_xor(gy, 1, 64);
        gz += __shfl_xor(gz, 1, 64);
        gx += __shfl_xor(gx, 2, 64);
        gy += __shfl_xor(gy, 2, 64);
        gz += __shfl_xor(gz, 2, 64);
        #pragma unroll
        for (int s = 4; s < 64; s <<= 1) {
            gx += __shfl_xor(gx, s, 64);
            gy += __shfl_xor(gy, s, 64);
            gz += __shfl_xor(gz, s, 64);
            tl[0] += __shfl_xor(tl[0], s, 64);
            tl[1] += __shfl_xor(tl[1], s, 64);
            tl[2] += __shfl_xor(tl[2], s, 64);
            tl[3] += __shfl_xor(tl[3], s, 64);
            tl[4] += __shfl_xor(tl[4], s, 64);
            tl[5] += __shfl_xor(tl[5], s, 64);
        }
        const float F = 128.0f / 3.0f;
        float gcx = F * gx;
        float gcy = F * gy;
        float gcz = F * gz;

        #pragma unroll
        for (int l = 0; l < L_; ++l)
            if ((lane >> 2) == l)
                o_s[lane] = tl[l] + b2r[l];
        asm volatile("s_waitcnt lgkmcnt(0)" ::: "memory");

        // ---- epilogue ----
        float olev[L_][4];
        #pragma unroll
        for (int l = 0; l < L_; ++l) {
            float4 ov = *(const float4*)&o_s[4 * l];
            olev[l][0] = ov.x; olev[l][1] = ov.y;
            olev[l][2] = ov.z; olev[l][3] = ov.w;
        }

        float r    = sqrtf(cx * cx + cy * cy + cz * cz);
        float smpl = r - 0.5f;
        float delta = 0.f;
        #pragma unroll
        for (int l = 0; l < L_; ++l) delta += olev[l][0];
        float sdf = smpl + delta;

        float ls[L_], sigma = 0.f;
        #pragma unroll
        for (int l = 0; l < L_; ++l) {
            float s = olev[l][0] + smpl;
            ls[l] = frcp(1.0f + fexp(s * rbeta)) * rbeta;
            sigma += ls[l];
        }
        float inv = frcp(sigma + 1e-8f);
        float sem[L_];
        #pragma unroll
        for (int l = 0; l < L_; ++l) sem[l] = ls[l] * inv;

        float r0 = 0.f, r1 = 0.f, r2 = 0.f;
        #pragma unroll
        for (int l = 0; l < L_; ++l) {
            r0 = fmaf(olev[l][1], sem[l], r0);
            r1 = fmaf(olev[l][2], sem[l], r1);
            r2 = fmaf(olev[l][3], sem[l], r2);
        }
        float rgb0 = frcp(1.0f + fexp(-r0)) * 1.002f - 0.001f;
        float rgb1 = frcp(1.0f + fexp(-r1)) * 1.002f - 0.001f;
        float rgb2 = frcp(1.0f + fexp(-r2)) * 1.002f - 0.001f;

        float rinv = frcp(r + 1e-8f);
        if (lane < 17) {
            float v =
                (lane == 0)  ? sdf :
                (lane == 1)  ? sigma :
                (lane == 2)  ? rgb0 :
                (lane == 3)  ? rgb1 :
                (lane == 4)  ? rgb2 :
                (lane == 5)  ? sem[0] :
                (lane == 6)  ? sem[1] :
                (lane == 7)  ? sem[2] :
                (lane == 8)  ? sem[3] :
                (lane == 9)  ? sem[4] :
                (lane == 10) ? sem[5] :
                (lane == 11) ? gcx + cx * rinv :
                (lane == 12) ? gcy + cy * rinv :
                (lane == 13) ? gcz + cz * rinv :
                (lane == 14) ? gcx :
                (lane == 15) ? gcy : gcz;
            out[(size_t)(gw * 8 + i) * 17 + lane] = v;
        }
    }
}

// ---------------------------------------------------------------------------
// Fallback (no workspace): original 1-point/wave kernel, f32 plane reads.
// ---------------------------------------------------------------------------
__global__ __launch_bounds__(256, 4) void point_fallback(
    const float* __restrict__ planes_f32,          // (NP,C,HW) f32
    const float* __restrict__ coords,
    const float* __restrict__ w1,
    const float* __restrict__ b1,
    const float* __restrict__ w2,
    const float* __restrict__ b2,
    const float* __restrict__ betap,
    float* __restrict__ out)
{
    __shared__ __align__(16) float feat_s[4][C_];
    __shared__ __align__(16) float dz_s[4][L_ * HID_];
    __shared__ __align__(16) float o_s[4][24];

    const int wave  = threadIdx.x >> 6;
    const int lane  = threadIdx.x & 63;
    const int point = blockIdx.x * 4 + wave;
    const int n     = point >> 16;

    const float cx = coords[point * 3 + 0];
    const float cy = coords[point * 3 + 1];
    const float cz = coords[point * 3 + 2];

    const float pjx[3] = {cx, cx, cz};
    const float pjy[3] = {cy, cz, cy};

    float wx0[3], wx1[3], wy0[3], wy1[3];
    int   pixi[3][4];
    float vmk[3][4];
    #pragma unroll
    for (int p = 0; p < 3; ++p) {
        float px = (pjx[p] + 1.0f) * 128.0f - 0.5f;
        float py = (pjy[p] + 1.0f) * 128.0f - 0.5f;
        float x0f = floorf(px), y0f = floorf(py);
        wx1[p] = px - x0f; wx0[p] = 1.0f - wx1[p];
        wy1[p] = py - y0f; wy0[p] = 1.0f - wy1[p];
        int x0 = (int)x0f, y0 = (int)y0f;
        int x1 = x0 + 1,  y1 = y0 + 1;
        int xc0 = min(max(x0, 0), 255), xc1 = min(max(x1, 0), 255);
        int yc0 = min(max(y0, 0), 255), yc1 = min(max(y1, 0), 255);
        float vx0 = (x0 >= 0 && x0 < 256) ? 1.f : 0.f;
        float vx1 = (x1 >= 0 && x1 < 256) ? 1.f : 0.f;
        float vy0 = (y0 >= 0 && y0 < 256) ? 1.f : 0.f;
        float vy1 = (y1 >= 0 && y1 < 256) ? 1.f : 0.f;
        pixi[p][0] = yc0 * 256 + xc0; vmk[p][0] = vx0 * vy0;
        pixi[p][1] = yc0 * 256 + xc1; vmk[p][1] = vx1 * vy0;
        pixi[p][2] = yc1 * 256 + xc0; vmk[p][2] = vx0 * vy1;
        pixi[p][3] = yc1 * 256 + xc1; vmk[p][3] = vx1 * vy1;
    }

    float g[3][4][3];
    #pragma unroll
    for (int p = 0; p < 3; ++p)
        #pragma unroll
        for (int ij = 0; ij < 4; ++ij)
            #pragma unroll
            for (int k = 0; k < 3; ++k) {
                int Cc = lane + 64 * k;
                size_t a = ((size_t)((n * 3 + p) * C_ + Cc)) * 65536 + pixi[p][ij];
                g[p][ij][k] = planes_f32[a] * vmk[p][ij];
            }

    #pragma unroll
    for (int k = 0; k < 3; ++k) {
        float f = 0.f;
        #pragma unroll
        for (int p = 0; p < 3; ++p) {
            f += wx0[p] * wy0[p] * g[p][0][k] + wx1[p] * wy0[p] * g[p][1][k]
               + wx0[p] * wy1[p] * g[p][2][k] + wx1[p] * wy1[p] * g[p][3][k];
        }
        feat_s[wave][lane + 64 * k] = f * (1.0f / 3.0f);
    }
    asm volatile("s_waitcnt lgkmcnt(0)" ::: "memory");

    #pragma unroll
    for (int l = 0; l < L_; ++l) {
        float b1l = b1[l * HID_ + lane];
        const float* w2l = w2 + (l * HID_ + lane) * 5;
        float w20 = w2l[0], w21 = w2l[1], w22 = w2l[2], w23 = w2l[3];

        float z0 = b1l, z1 = 0.f;
        #pragma unroll
        for (int q = 0; q < 8; ++q) {
            float4 fv = *(const float4*)&feat_s[wave][l * CPL_ + 4 * q];
            z0 = fmaf(fv.x, w1[(l * CPL_ + 4 * q + 0) * HID_ + lane], z0);
            z1 = fmaf(fv.y, w1[(l * CPL_ + 4 * q + 1) * HID_ + lane], z1);
            z0 = fmaf(fv.z, w1[(l * CPL_ + 4 * q + 2) * HID_ + lane], z0);
            z1 = fmaf(fv.w, w1[(l * CPL_ + 4 * q + 3) * HID_ + lane], z1);
        }
        float z  = z0 + z1;
        float e  = expf(-fabsf(z));
        float sp = fmaxf(z, 0.f) + log1pf(e);
        float sg = ((z > 0.f) ? 1.0f : e) / (1.0f + e);
        dz_s[wave][l * HID_ + lane] = sg * w20;

        float o0 = sp * w20, o1 = sp * w21, o2 = sp * w22, o3 = sp * w23;
        float u  = (lane & 1) ? o1 : o0;
        float uw = (lane & 1) ? o0 : o1;
        u += __shfl_xor(uw, 1, 64);
        float v  = (lane & 1) ? o3 : o2;
        float vw = (lane & 1) ? o2 : o3;
        v += __shfl_xor(vw, 1, 64);
        float tt = (lane & 2) ? v : u;
        float tw = (lane & 2) ? u : v;
        tt += __shfl_xor(tw, 2, 64);
        tt += __shfl_xor(tt, 4, 64);
        tt += __shfl_xor(tt, 8, 64);
        tt += __shfl_xor(tt, 16, 64);
        tt += __shfl_xor(tt, 32, 64);
        if ((lane >> 2) == l)
            o_s[wave][lane] = tt + b2[l * 5 + (lane & 3)];
    }
    asm volatile("s_waitcnt lgkmcnt(0)" ::: "memory");

    float df[3];
    #pragma unroll
    for (int k = 0; k < 3; ++k) {
        int cg = lane + 64 * k;
        const float* w1r = w1 + cg * HID_;
        const float* dzr = &dz_s[wave][(cg >> 5) * HID_];
        float a0 = 0.f, a1 = 0.f;
        #pragma unroll
        for (int h4 = 0; h4 < 16; ++h4) {
            float4 wv = *(const float4*)(w1r + 4 * h4);
            float4 dv = *(const float4*)(dzr + 4 * h4);
            a0 = fmaf(wv.x, dv.x, a0);
            a1 = fmaf(wv.y, dv.y, a1);
            a0 = fmaf(wv.z, dv.z, a0);
            a1 = fmaf(wv.w, dv.w, a1);
        }
        df[k] = a0 + a1;
    }

    float ax[3] = {0.f, 0.f, 0.f};
    float ay[3] = {0.f, 0.f, 0.f};
    #pragma unroll
    for (int k = 0; k < 3; ++k)
        #pragma unroll
        for (int p = 0; p < 3; ++p) {
            ax[p] = fmaf(df[k], wy0[p] * (g[p][1][k] - g[p][0][k])
                               + wy1[p] * (g[p][3][k] - g[p][2][k]), ax[p]);
            ay[p] = fmaf(df[k], wx0[p] * (g[p][2][k] - g[p][0][k])
                               + wx1[p] * (g[p][3][k] - g[p][1][k]), ay[p]);
        }
    #pragma unroll
    for (int s = 1; s < 64; s <<= 1) {
        ax[0] += __shfl_xor(ax[0], s, 64);
        ax[1] += __shfl_xor(ax[1], s, 64);
        ax[2] += __shfl_xor(ax[2], s, 64);
        ay[0] += __shfl_xor(ay[0], s, 64);
        ay[1] += __shfl_xor(ay[1], s, 64);
        ay[2] += __shfl_xor(ay[2], s, 64);
    }
    const float F = 128.0f / 3.0f;
    float gcx = F * (ax[0] + ax[1]);
    float gcy = F * (ay[0] + ay[2]);
    float gcz = F * (ay[1] + ax[2]);

    const float beta = betap[0];
    float olev[L_][4];
    #pragma unroll
    for (int l = 0; l < L_; ++l) {
        float4 ov = *(const float4*)&o_s[wave][4 * l];
        olev[l][0] = ov.x; olev[l][1] = ov.y;
        olev[l][2] = ov.z; olev[l][3] = ov.w;
    }

    float r    = sqrtf(cx * cx + cy * cy + cz * cz);
    float smpl = r - 0.5f;
    float delta = 0.f;
    #pragma unroll
    for (int l = 0; l < L_; ++l) delta += olev[l][0];
    float sdf = smpl + delta;

    float ls[L_], sigma = 0.f;
    #pragma unroll
    for (int l = 0; l < L_; ++l) {
        float s = olev[l][0] + smpl;
        ls[l] = (1.0f / (1.0f + expf(s / beta))) / beta;
        sigma += ls[l];
    }
    float inv = 1.0f / (sigma + 1e-8f);
    float sem[L_];
    #pragma unroll
    for (int l = 0; l < L_; ++l) sem[l] = ls[l] * inv;

    float r0 = 0.f, r1 = 0.f, r2 = 0.f;
    #pragma unroll
    for (int l = 0; l < L_; ++l) {
        r0 = fmaf(olev[l][1], sem[l], r0);
        r1 = fmaf(olev[l][2], sem[l], r1);
        r2 = fmaf(olev[l][3], sem[l], r2);
    }
    float rgb0 = (1.0f / (1.0f + expf(-r0))) * 1.002f - 0.001f;
    float rgb1 = (1.0f / (1.0f + expf(-r1))) * 1.002f - 0.001f;
    float rgb2 = (1.0f / (1.0f + expf(-r2))) * 1.002f - 0.001f;

    float rinv = 1.0f / (r + 1e-8f);
    if (lane < 17) {
        float v =
            (lane == 0)  ? sdf :
            (lane == 1)  ? sigma :
            (lane == 2)  ? rgb0 :
            (lane == 3)  ? rgb1 :
            (lane == 4)  ? rgb2 :
            (lane == 5)  ? sem[0] :
            (lane == 6)  ? sem[1] :
            (lane == 7)  ? sem[2] :
            (lane == 8)  ? sem[3] :
            (lane == 9)  ? sem[4] :
            (lane == 10) ? sem[5] :
            (lane == 11) ? gcx + cx * rinv :
            (lane == 12) ? gcy + cy * rinv :
            (lane == 13) ? gcz + cz * rinv :
            (lane == 14) ? gcx :
            (lane == 15) ? gcy : gcz;
        out[(size_t)point * 17 + lane] = v;
    }
}

extern "C" void kernel_launch(void* const* d_in, const int* in_sizes, int n_in,
                              void* d_out, int out_size, void* d_ws, size_t ws_size,
                              hipStream_t stream)
{
    const float* planes = (const float*)d_in[0];
    const float* coords = (const float*)d_in[1];
    const float* w1     = (const float*)d_in[2];
    const float* b1     = (const float*)d_in[3];
    const float* w2     = (const float*)d_in[4];
    const float* b2     = (const float*)d_in[5];
    const float* beta   = (const float*)d_in[6];
    float* out = (float*)d_out;

    const size_t need = (size_t)6 * 65536 * C_ * sizeof(unsigned short); // 151 MB
    const int shmem = 19232 * 4;   // 76928 B dynamic LDS for point2

    if (ws_size >= need) {
        static bool attr_done = false;
        if (!attr_done) {
            (void)hipFuncSetAttribute(reinterpret_cast<const void*>(&point2),
                                      hipFuncAttributeMaxDynamicSharedMemorySize,
                                      shmem);
            attr_done = true;
        }
        unsigned short* tp = (unsigned short*)d_ws;
        transpose_kernel<<<6 * 2048, 256, 0, stream>>>(planes, tp);
        point2<<<2048, 512, shmem, stream>>>(
            tp, coords, w1, b1, w2, b2, beta, out);
    } else {
        point_fallback<<<131072 / 4, 256, 0, stream>>>(
            planes, coords, w1, b1, w2, b2, beta, out);
    }
}